// Round 1
// baseline (536.397 us; speedup 1.0000x reference)
//
#include <hip/hip_runtime.h>
#include <math.h>

// Problem constants
//  B=64, CH=64, T_IN=32, N_OSC=32, BAND=16384, N_NOISE_FRAMES=4096, NOISE_STEP=4
//  N_UP=7, LOWEST_FREQ = 20/11025
#define LOWEST_FREQ_F 0.00181405895691609977f

__device__ __forceinline__ float lrelu(float x) { return x > 0.f ? x : 0.2f * x; }

__device__ __forceinline__ float sin_rev(float fr) {
  // sin(2*pi*fr); fr in [0,1)
  return __builtin_amdgcn_sinf(fr);
}

// ---------------------------------------------------------------------------
// Frontend: x (B,32,64) -> 4x [conv3 + leaky] -> conv3  => z (64ch x 32t) in LDS
// then: y0 = nz_init(z)  (B,64,32) to global,
//       amp/freq projections (B,32,32) to global,
//       fp64 phase-boundary prefix sums -> ph = frac(P[i]/2) (B,32,32) f32.
// One block per batch element.
// ---------------------------------------------------------------------------
__global__ __launch_bounds__(256) void frontend_kernel(
    const float* __restrict__ x,
    const float* __restrict__ net_w, const float* __restrict__ net_b,
    const float* __restrict__ fin_w, const float* __restrict__ fin_b,
    const float* __restrict__ amp_w, const float* __restrict__ amp_b,
    const float* __restrict__ frq_w, const float* __restrict__ frq_b,
    const float* __restrict__ nzi_w, const float* __restrict__ nzi_b,
    float* __restrict__ y0, float* __restrict__ amp_o,
    float* __restrict__ frq_o, float* __restrict__ ph_o)
{
  // smem overlay: conv weights half (96*65=6240 floats) | wil(4096) | awl(2048)+fwl(2048)
  __shared__ __align__(16) float smem[6240];
  __shared__ __align__(16) float za[2304];   // 64 ch x 36 (col0 & col33 are zero pads)
  __shared__ __align__(16) float zb[2304];
  __shared__ float fl[1056];                  // freq values [o*33 + t]

  const int b   = blockIdx.x;
  const int tid = threadIdx.x;
  const int co  = tid & 63;
  const int q   = tid >> 6;

  // load x[b] (t,c) -> za[c][t+1]; zero the pads of both buffers
  for (int idx = tid; idx < 2048; idx += 256) {
    int t = idx >> 6, c = idx & 63;
    za[c*36 + t + 1] = x[b*2048 + idx];
  }
  if (tid < 64) {
    za[tid*36] = 0.f; za[tid*36 + 33] = 0.f;
    zb[tid*36] = 0.f; zb[tid*36 + 33] = 0.f;
  }

  float* pa = za;
  float* pb = zb;
  for (int l = 0; l < 5; ++l) {
    const float* wsrc = (l < 4) ? (net_w + l*12288) : fin_w;
    const float* bsrc = (l < 4) ? (net_b + l*64)   : fin_b;
    float acc[8];
    {
      float bv = bsrc[co];
      #pragma unroll
      for (int j = 0; j < 8; ++j) acc[j] = bv;
    }
    for (int h = 0; h < 2; ++h) {
      __syncthreads();  // WAR on smem (and covers initial za load / prev layer writes)
      for (int idx = tid; idx < 6144; idx += 256) {
        int o = idx / 96, rem = idx - o*96;
        smem[rem*65 + o] = wsrc[o*192 + h*96 + rem];
      }
      __syncthreads();
      for (int ci = 0; ci < 32; ++ci) {
        const float* row = pa + (h*32 + ci)*36 + q*8;
        float rr[12];
        #pragma unroll
        for (int i = 0; i < 3; ++i) {
          float4 v = *(const float4*)(row + 4*i);
          rr[4*i+0]=v.x; rr[4*i+1]=v.y; rr[4*i+2]=v.z; rr[4*i+3]=v.w;
        }
        float w0 = smem[(ci*3+0)*65 + co];
        float w1 = smem[(ci*3+1)*65 + co];
        float w2 = smem[(ci*3+2)*65 + co];
        #pragma unroll
        for (int j = 0; j < 8; ++j)
          acc[j] += w0*rr[j] + w1*rr[j+1] + w2*rr[j+2];
      }
    }
    const bool act = (l < 4);
    #pragma unroll
    for (int j = 0; j < 8; ++j) {
      float v = acc[j];
      pb[co*36 + q*8 + j + 1] = act ? lrelu(v) : v;
    }
    float* tp = pa; pa = pb; pb = tp;
  }
  __syncthreads();
  const float* zf = pa;  // final z, 64ch x 32t (+pads)

  // ---- y0 = nz_init 1x1 conv ----
  for (int idx = tid; idx < 4096; idx += 256) {
    int o = idx >> 6, c = idx & 63;
    smem[c*64 + o] = nzi_w[idx];
  }
  __syncthreads();
  {
    float acc[8];
    float bv = nzi_b[co];
    #pragma unroll
    for (int j = 0; j < 8; ++j) acc[j] = bv;
    for (int c = 0; c < 64; ++c) {
      float wv = smem[c*64 + co];
      const float* rw = zf + c*36 + q*8 + 1;
      #pragma unroll
      for (int j = 0; j < 8; ++j) acc[j] += wv * rw[j];
    }
    float* yp = y0 + (b*64 + co)*32 + q*8;
    *(float4*)yp       = make_float4(acc[0], acc[1], acc[2], acc[3]);
    *(float4*)(yp + 4) = make_float4(acc[4], acc[5], acc[6], acc[7]);
  }
  __syncthreads();

  // ---- amp / freq projections ----
  for (int idx = tid; idx < 2048; idx += 256) {
    int o = idx >> 6, c = idx & 63;
    smem[c*32 + o]        = amp_w[idx];
    smem[2048 + c*32 + o] = frq_w[idx];
  }
  __syncthreads();
  for (int tt = 0; tt < 4; ++tt) {
    int task = tid + 256*tt;
    int o = task & 31, t = task >> 5;
    float aa = amp_b[o], ff = frq_b[o];
    for (int c = 0; c < 64; ++c) {
      float zv = zf[c*36 + t + 1];
      aa += smem[c*32 + o] * zv;
      ff += smem[2048 + c*32 + o] * zv;
    }
    aa = fabsf(aa);
    float sg = 1.f / (1.f + expf(-ff));
    float fq = LOWEST_FREQ_F + sg * (1.f - LOWEST_FREQ_F);
    amp_o[b*1024 + o*32 + t] = aa;
    frq_o[b*1024 + o*32 + t] = fq;
    fl[o*33 + t] = fq;
  }
  __syncthreads();

  // ---- fp64 phase boundary prefix: P[i] = sum of freq through sample 255+512*i
  // store frac(P[i]/2)  (sin(pi*S) = sin_rev(frac(S/2)))
  if (tid < 32) {
    const int o = tid;
    double P = 256.0 * (double)fl[o*33];
    double h = P * 0.5;
    ph_o[b*1024 + o*32] = (float)(h - floor(h));
    for (int i = 1; i < 32; ++i) {
      P += 256.0 * ((double)fl[o*33 + i - 1] + (double)fl[o*33 + i]);
      h = P * 0.5;
      ph_o[b*1024 + o*32 + i] = (float)(h - floor(h));
    }
  }
}

// ---------------------------------------------------------------------------
// Noise stack layer: nearest-2x upsample + conv3(pad1) + leaky.
// in (B,64,Tin) -> out (B,64,2*Tin). TT outputs per block along T.
// ---------------------------------------------------------------------------
template<int TT>
__global__ __launch_bounds__(256) void up_conv_kernel(
    const float* __restrict__ in, float* __restrict__ out,
    const float* __restrict__ w, const float* __restrict__ bias, int Tin)
{
  constexpr int NT  = TT / 4;                 // outputs per thread
  constexpr int NR4 = (NT/2 + 2 + 3) / 4;     // float4 window reads
  constexpr int RS  = 3*(NT/2) + 4*NR4;       // LDS row stride (mult of 4)
  constexpr int RIN = TT/2 + 2;               // input samples needed
  __shared__ __align__(16) float wl[96*65];   // half the weights, [ (ci*3+k) ][ co ], +pad
  __shared__ __align__(16) float tile[64*RS];

  const int b    = blockIdx.y;
  const int T0   = blockIdx.x * TT;
  const int Tout = 2 * Tin;
  const int tid  = threadIdx.x;

  // stage input tile: row ci, col p  <->  global sample g = T0/2 - 1 + p
  {
    const int ci = tid >> 2;
    const float* inb = in + ((size_t)b*64 + ci) * Tin;
    const int gbase = T0/2 - 1;
    for (int p = (tid & 3); p < RIN; p += 4) {
      int g = gbase + p;
      tile[ci*RS + p] = (g >= 0 && g < Tin) ? inb[g] : 0.f;
    }
  }

  const int co = tid & 63;
  const int q  = tid >> 6;
  float acc[NT];
  {
    float bv = bias[co];
    #pragma unroll
    for (int j = 0; j < NT; ++j) acc[j] = bv;
  }

  for (int h = 0; h < 2; ++h) {
    if (h) __syncthreads();  // WAR before restaging weights
    for (int idx = tid; idx < 6144; idx += 256) {
      int o = idx / 96, rem = idx - o*96;
      wl[rem*65 + o] = w[o*192 + h*96 + rem];
    }
    __syncthreads();
    #pragma unroll 2
    for (int ci = 0; ci < 32; ++ci) {
      const float* trow = tile + (h*32 + ci)*RS + q*(NT/2);
      float r[NR4*4];
      #pragma unroll
      for (int i = 0; i < NR4; ++i) {
        float4 v = *(const float4*)(trow + 4*i);
        r[4*i+0]=v.x; r[4*i+1]=v.y; r[4*i+2]=v.z; r[4*i+3]=v.w;
      }
      float w0 = wl[(ci*3+0)*65 + co];
      float w1 = wl[(ci*3+1)*65 + co];
      float w2 = wl[(ci*3+2)*65 + co];
      #pragma unroll
      for (int j = 0; j < NT; ++j)
        acc[j] += w0*r[(j+1)>>1] + w1*r[(j+2)>>1] + w2*r[(j+3)>>1];
    }
  }

  float* outp = out + ((size_t)b*64 + co)*Tout + T0 + q*NT;
  #pragma unroll
  for (int j = 0; j < NT; j += 4) {
    float4 v;
    v.x = lrelu(acc[j+0]);
    v.y = lrelu(acc[j+1]);
    v.z = lrelu(acc[j+2]);
    v.w = lrelu(acc[j+3]);
    *(float4*)(outp + j) = v;
  }
}

// ---------------------------------------------------------------------------
// Oscillator bank: harm[b,t] = sum_o amp(b,o,t)*sin(pi*S(b,o,t))
// S reconstructed O(1) from fp64 boundary table (stored as frac(P/2), f32).
// Writes out (not +=): runs before nz_final_kernel.
// ---------------------------------------------------------------------------
__global__ __launch_bounds__(256) void osc_kernel(
    const float* __restrict__ amp, const float* __restrict__ frq,
    const float* __restrict__ ph, float* __restrict__ out)
{
  __shared__ float al[1024], fq[1024], pl[1024];
  const int b   = blockIdx.y;
  const int T0  = blockIdx.x * 1024;
  const int tid = threadIdx.x;
  for (int i = tid; i < 1024; i += 256) {
    al[i] = amp[b*1024 + i];
    fq[i] = frq[b*1024 + i];
    pl[i] = ph[b*1024 + i];
  }
  __syncthreads();
  #pragma unroll
  for (int j = 0; j < 4; ++j) {
    const int t = T0 + tid + 256*j;
    float acc = 0.f;
    if (t < 256) {                       // clipped head: freq=f0, amp=a0
      const float tp = (float)(t + 1) * 0.5f;
      for (int o = 0; o < 32; ++o) {
        float v  = tp * fq[o*32];
        float fr = v - floorf(v);
        acc += al[o*32] * sin_rev(fr);
      }
    } else if (t >= 16128) {             // clipped tail: freq=f31, amp=a31
      const float tp = (float)(t - 16127) * 0.5f;
      for (int o = 0; o < 32; ++o) {
        float v  = pl[o*32 + 31] + tp * fq[o*32 + 31];
        float fr = v - floorf(v);
        acc += al[o*32 + 31] * sin_rev(fr);
      }
    } else {
      const int i = (t - 256) >> 9;
      const int m = (t - 256) & 511;
      const float mm = (float)(m + 1);
      const float fa = ((float)m + 0.5f) * (1.f/512.f);   // amp lerp frac
      const float mq = mm * mm * (1.f/1024.f);            // sum of fracs
      for (int o = 0; o < 32; ++o) {
        float f0 = fq[o*32 + i], f1 = fq[o*32 + i + 1];
        float a0 = al[o*32 + i], a1 = al[o*32 + i + 1];
        float av = a0 + (a1 - a0) * fa;
        float part = mm * f0 + (f1 - f0) * mq;            // sum over cell prefix
        float v  = pl[o*32 + i] + part * 0.5f;
        float fr = v - floorf(v);
        acc += av * sin_rev(fr);
      }
    }
    out[b*16384 + t] = acc;
  }
}

// ---------------------------------------------------------------------------
// Final 1x1 conv to 3 rfft coeffs, square, apply length-4 ortho rfft/irfft
// filter to uniform noise, accumulate into out.
// ---------------------------------------------------------------------------
__global__ __launch_bounds__(256) void nz_final_kernel(
    const float* __restrict__ y, const float* __restrict__ noise,
    const float* __restrict__ w, const float* __restrict__ bias,
    float* __restrict__ out)
{
  __shared__ float wl[192];
  const int tid = threadIdx.x;
  if (tid < 192) {
    int o = tid >> 6, c = tid & 63;
    wl[c*3 + o] = w[tid];
  }
  __syncthreads();
  const int f  = blockIdx.x * 256 + tid;   // global frame id, 0..262143
  const int b  = f >> 12, fr = f & 4095;
  const float* yb = y + ((size_t)b*64) * 4096 + fr;
  float c0 = bias[0], c1 = bias[1], c2 = bias[2];
  #pragma unroll 4
  for (int c = 0; c < 64; ++c) {
    float yv = yb[(size_t)c * 4096];
    c0 += wl[c*3+0] * yv;
    c1 += wl[c*3+1] * yv;
    c2 += wl[c*3+2] * yv;
  }
  c0 *= c0; c1 *= c1; c2 *= c2;
  const float4 n = *(const float4*)(noise + (size_t)f*4);
  // rfft(n, ortho): X0=(s)/2, X1=((n0-n2) - i(n1-n3))/2, X2=(n0-n1+n2-n3)/2
  float F0  = c0 * (n.x + n.y + n.z + n.w) * 0.5f;
  float F1r = c1 * (n.x - n.z) * 0.5f;
  float F1i = -(c1 * (n.y - n.w) * 0.5f);
  float F2  = c2 * (n.x - n.y + n.z - n.w) * 0.5f;
  // irfft ortho, N=4: x_j = 0.5*(F0 + 2*Re(F1 e^{i pi j/2}) + F2*(-1)^j)
  float4 r = *(float4*)(out + (size_t)f*4);
  r.x += 0.5f * (F0 + 2.f*F1r + F2);
  r.y += 0.5f * (F0 - 2.f*F1i - F2);
  r.z += 0.5f * (F0 - 2.f*F1r + F2);
  r.w += 0.5f * (F0 + 2.f*F1i - F2);
  *(float4*)(out + (size_t)f*4) = r;
}

// ---------------------------------------------------------------------------
extern "C" void kernel_launch(void* const* d_in, const int* in_sizes, int n_in,
                              void* d_out, int out_size, void* d_ws, size_t ws_size,
                              hipStream_t stream) {
  (void)in_sizes; (void)n_in; (void)out_size; (void)ws_size;
  const float* x     = (const float*)d_in[0];
  const float* noise = (const float*)d_in[1];
  const float* net_w = (const float*)d_in[2];
  const float* net_b = (const float*)d_in[3];
  const float* fin_w = (const float*)d_in[4];
  const float* fin_b = (const float*)d_in[5];
  const float* amp_w = (const float*)d_in[6];
  const float* amp_b = (const float*)d_in[7];
  const float* frq_w = (const float*)d_in[8];
  const float* frq_b = (const float*)d_in[9];
  const float* nzi_w = (const float*)d_in[10];
  const float* nzi_b = (const float*)d_in[11];
  const float* nzu_w = (const float*)d_in[12];
  const float* nzu_b = (const float*)d_in[13];
  const float* nzf_w = (const float*)d_in[14];
  const float* nzf_b = (const float*)d_in[15];
  float* out = (float*)d_out;

  // workspace layout (requires ~129 MiB):
  //   bufA: 64*64*4096 f32 (64 MiB)   bufB: same (64 MiB)
  //   amp (B,32,32) | freq (B,32,32) | ph (B,32,32)   (256 KiB each)
  float* bufA = (float*)d_ws;
  float* bufB = bufA + (size_t)64*64*4096;
  float* ampv = bufB + (size_t)64*64*4096;
  float* frqv = ampv + 65536;
  float* phv  = frqv + 65536;

  frontend_kernel<<<dim3(64), dim3(256), 0, stream>>>(
      x, net_w, net_b, fin_w, fin_b, amp_w, amp_b, frq_w, frq_b,
      nzi_w, nzi_b, bufA, ampv, frqv, phv);

  // noise stack: y0(T=32,bufA) -> ... -> y7(T=4096,bufB)
  up_conv_kernel<64> <<<dim3(1, 64), dim3(256), 0, stream>>>(bufA, bufB, nzu_w + 0*12288, nzu_b + 0*64, 32);
  up_conv_kernel<128><<<dim3(1, 64), dim3(256), 0, stream>>>(bufB, bufA, nzu_w + 1*12288, nzu_b + 1*64, 64);
  up_conv_kernel<128><<<dim3(2, 64), dim3(256), 0, stream>>>(bufA, bufB, nzu_w + 2*12288, nzu_b + 2*64, 128);
  up_conv_kernel<128><<<dim3(4, 64), dim3(256), 0, stream>>>(bufB, bufA, nzu_w + 3*12288, nzu_b + 3*64, 256);
  up_conv_kernel<128><<<dim3(8, 64), dim3(256), 0, stream>>>(bufA, bufB, nzu_w + 4*12288, nzu_b + 4*64, 512);
  up_conv_kernel<128><<<dim3(16,64), dim3(256), 0, stream>>>(bufB, bufA, nzu_w + 5*12288, nzu_b + 5*64, 1024);
  up_conv_kernel<128><<<dim3(32,64), dim3(256), 0, stream>>>(bufA, bufB, nzu_w + 6*12288, nzu_b + 6*64, 2048);

  osc_kernel<<<dim3(16, 64), dim3(256), 0, stream>>>(ampv, frqv, phv, out);
  nz_final_kernel<<<dim3(1024), dim3(256), 0, stream>>>(bufB, noise, nzf_w, nzf_b, out);
}

// Round 2
// 257.919 us; speedup vs baseline: 2.0797x; 2.0797x over previous
//
#include <hip/hip_runtime.h>
#include <math.h>

// Problem constants
//  B=64, CH=64, T_IN=32, N_OSC=32, BAND=16384, N_NOISE_FRAMES=4096, NOISE_STEP=4
//  N_UP=7, LOWEST_FREQ = 20/11025
#define LOWEST_FREQ_F 0.00181405895691609977f

typedef short bf16x8 __attribute__((ext_vector_type(8)));
typedef float f32x16 __attribute__((ext_vector_type(16)));

__device__ __forceinline__ float lrelu(float x) { return x > 0.f ? x : 0.2f * x; }
__device__ __forceinline__ float sin_rev(float fr) { return __builtin_amdgcn_sinf(fr); }
__device__ __forceinline__ float bf2f(unsigned short u) {
  union { unsigned int i; float f; } x; x.i = ((unsigned int)u) << 16; return x.f;
}
__device__ __forceinline__ unsigned short f2bf(float f) {
  union { float f; unsigned int i; } x; x.f = f;
  unsigned int r = x.i + 0x7FFFu + ((x.i >> 16) & 1u);   // RNE
  return (unsigned short)(r >> 16);
}

// ---------------------------------------------------------------------------
// Fold conv weights for the even/odd decomposition, f32 -> bf16:
//   pd=0: w0   pd=1: w1+w2   pd=2: w0+w1   pd=3: w2
// wf layout: [l][pd][co][ci]   (7*4*64*64)
// ---------------------------------------------------------------------------
__global__ __launch_bounds__(256) void fold_w_kernel(
    const float* __restrict__ w, short* __restrict__ wf)
{
  int idx = blockIdx.x * 256 + threadIdx.x;
  if (idx >= 7 * 16384) return;
  int l = idx >> 14, r = idx & 16383;
  int pd = r >> 12, co = (r >> 6) & 63, ci = r & 63;
  const float* wb = w + l * 12288 + co * 192 + ci * 3;
  float v;
  if      (pd == 0) v = wb[0];
  else if (pd == 1) v = wb[1] + wb[2];
  else if (pd == 2) v = wb[0] + wb[1];
  else              v = wb[2];
  wf[idx] = (short)f2bf(v);
}

// ---------------------------------------------------------------------------
// Frontend: x (B,32,64) -> 4x [conv3 + leaky] -> conv3  => z (64ch x 32t) in LDS
// then: y0 = nz_init(z) (bf16, (B,64,32)) to global,
//       amp/freq projections (B,32,32) to global,
//       fp64 phase-boundary prefix sums -> ph = frac(P[i]/2) (B,32,32) f32.
// One block per batch element.
// ---------------------------------------------------------------------------
__global__ __launch_bounds__(256) void frontend_kernel(
    const float* __restrict__ x,
    const float* __restrict__ net_w, const float* __restrict__ net_b,
    const float* __restrict__ fin_w, const float* __restrict__ fin_b,
    const float* __restrict__ amp_w, const float* __restrict__ amp_b,
    const float* __restrict__ frq_w, const float* __restrict__ frq_b,
    const float* __restrict__ nzi_w, const float* __restrict__ nzi_b,
    unsigned short* __restrict__ y0, float* __restrict__ amp_o,
    float* __restrict__ frq_o, float* __restrict__ ph_o)
{
  __shared__ __align__(16) float smem[6240];
  __shared__ __align__(16) float za[2304];   // 64 ch x 36 (col0 & col33 zero pads)
  __shared__ __align__(16) float zb[2304];
  __shared__ float fl[1056];                 // freq values [o*33 + t]

  const int b   = blockIdx.x;
  const int tid = threadIdx.x;
  const int co  = tid & 63;
  const int q   = tid >> 6;

  for (int idx = tid; idx < 2048; idx += 256) {
    int t = idx >> 6, c = idx & 63;
    za[c*36 + t + 1] = x[b*2048 + idx];
  }
  if (tid < 64) {
    za[tid*36] = 0.f; za[tid*36 + 33] = 0.f;
    zb[tid*36] = 0.f; zb[tid*36 + 33] = 0.f;
  }

  float* pa = za;
  float* pb = zb;
  for (int l = 0; l < 5; ++l) {
    const float* wsrc = (l < 4) ? (net_w + l*12288) : fin_w;
    const float* bsrc = (l < 4) ? (net_b + l*64)   : fin_b;
    float acc[8];
    {
      float bv = bsrc[co];
      #pragma unroll
      for (int j = 0; j < 8; ++j) acc[j] = bv;
    }
    for (int h = 0; h < 2; ++h) {
      __syncthreads();
      for (int idx = tid; idx < 6144; idx += 256) {
        int o = idx / 96, rem = idx - o*96;
        smem[rem*65 + o] = wsrc[o*192 + h*96 + rem];
      }
      __syncthreads();
      for (int ci = 0; ci < 32; ++ci) {
        const float* row = pa + (h*32 + ci)*36 + q*8;
        float rr[12];
        #pragma unroll
        for (int i = 0; i < 3; ++i) {
          float4 v = *(const float4*)(row + 4*i);
          rr[4*i+0]=v.x; rr[4*i+1]=v.y; rr[4*i+2]=v.z; rr[4*i+3]=v.w;
        }
        float w0 = smem[(ci*3+0)*65 + co];
        float w1 = smem[(ci*3+1)*65 + co];
        float w2 = smem[(ci*3+2)*65 + co];
        #pragma unroll
        for (int j = 0; j < 8; ++j) {
          acc[j] = fmaf(w0, rr[j],   acc[j]);
          acc[j] = fmaf(w1, rr[j+1], acc[j]);
          acc[j] = fmaf(w2, rr[j+2], acc[j]);
        }
      }
    }
    const bool act = (l < 4);
    #pragma unroll
    for (int j = 0; j < 8; ++j) {
      float v = acc[j];
      pb[co*36 + q*8 + j + 1] = act ? lrelu(v) : v;
    }
    float* tp = pa; pa = pb; pb = tp;
  }
  __syncthreads();
  const float* zf = pa;  // final z, 64ch x 32t (+pads)

  // ---- y0 = nz_init 1x1 conv -> bf16 ----
  for (int idx = tid; idx < 4096; idx += 256) {
    int o = idx >> 6, c = idx & 63;
    smem[c*64 + o] = nzi_w[idx];
  }
  __syncthreads();
  {
    float acc[8];
    float bv = nzi_b[co];
    #pragma unroll
    for (int j = 0; j < 8; ++j) acc[j] = bv;
    for (int c = 0; c < 64; ++c) {
      float wv = smem[c*64 + co];
      const float* rw = zf + c*36 + q*8 + 1;
      #pragma unroll
      for (int j = 0; j < 8; ++j) acc[j] = fmaf(wv, rw[j], acc[j]);
    }
    unsigned short* yp = y0 + (b*64 + co)*32 + q*8;
    #pragma unroll
    for (int j = 0; j < 8; ++j) yp[j] = f2bf(acc[j]);
  }
  __syncthreads();

  // ---- amp / freq projections ----
  for (int idx = tid; idx < 2048; idx += 256) {
    int o = idx >> 6, c = idx & 63;
    smem[c*32 + o]        = amp_w[idx];
    smem[2048 + c*32 + o] = frq_w[idx];
  }
  __syncthreads();
  for (int tt = 0; tt < 4; ++tt) {
    int task = tid + 256*tt;
    int o = task & 31, t = task >> 5;
    float aa = amp_b[o], ff = frq_b[o];
    for (int c = 0; c < 64; ++c) {
      float zv = zf[c*36 + t + 1];
      aa = fmaf(smem[c*32 + o], zv, aa);
      ff = fmaf(smem[2048 + c*32 + o], zv, ff);
    }
    aa = fabsf(aa);
    float sg = 1.f / (1.f + expf(-ff));
    float fq = LOWEST_FREQ_F + sg * (1.f - LOWEST_FREQ_F);
    amp_o[b*1024 + o*32 + t] = aa;
    frq_o[b*1024 + o*32 + t] = fq;
    fl[o*33 + t] = fq;
  }
  __syncthreads();

  // ---- fp64 phase boundary prefix: store frac(P[i]/2) ----
  if (tid < 32) {
    const int o = tid;
    double P = 256.0 * (double)fl[o*33];
    double h = P * 0.5;
    ph_o[b*1024 + o*32] = (float)(h - floor(h));
    for (int i = 1; i < 32; ++i) {
      P += 256.0 * ((double)fl[o*33 + i - 1] + (double)fl[o*33 + i]);
      h = P * 0.5;
      ph_o[b*1024 + o*32 + i] = (float)(h - floor(h));
    }
  }
}

// ---------------------------------------------------------------------------
// MFMA up-conv layer (nearest-2x upsample + conv3 + leaky), even/odd folded:
//   out[2s]   = lrelu(b + sum_ci w0*in[s-1] + (w1+w2)*in[s])
//   out[2s+1] = lrelu(b + sum_ci (w0+w1)*in[s] + w2*in[s+1])
// in/out bf16 (B,64,T). A (folded weights) register-resident; B staged in LDS.
// v_mfma_f32_32x32x16_bf16:  A[m=L&31][k=(L>>5)*8+j], B[k=(L>>5)*8+j][n=L&31],
//                            D col=L&31, row=(r&3)+8*(r>>2)+4*(L>>5).
// Block: M=64 (2 m-tiles), STILE s-columns; wave = (m-tile, n-group).
// ---------------------------------------------------------------------------
template<int STILE>
__global__ __launch_bounds__(256) void mfma_up_kernel(
    const unsigned short* __restrict__ in, unsigned short* __restrict__ out,
    const short* __restrict__ wf, const float* __restrict__ bias, int Tin)
{
  constexpr int ROWS = STILE + 2;
  constexpr int RSB  = 72;            // LDS row stride (bf16 units) = 144 B (16B-mult, conflict-free)
  constexpr int G    = STILE / 64;    // n-tiles per wave
  __shared__ __align__(16) short lB[ROWS * RSB];

  const int b   = blockIdx.y;
  const int s0  = blockIdx.x * STILE;
  const int tid = threadIdx.x;
  const int L   = tid & 63;
  const int w   = tid >> 6;
  const int mt  = w & 1;
  const int ng  = w >> 1;

  // A fragments (held in registers): wf[pd][co][ci], 16B-contiguous in ci
  bf16x8 Af[4][4];
  {
    const short* wb = wf + (mt*32 + (L & 31))*64 + ((L >> 5) << 3);
    #pragma unroll
    for (int pd = 0; pd < 4; ++pd)
      #pragma unroll
      for (int ks = 0; ks < 4; ++ks)
        Af[pd][ks] = *(const bf16x8*)(wb + pd*4096 + ks*16);
  }

  // stage input rows g = s0-1 .. s0+STILE (zero-padded) into LDS
  for (int idx = tid; idx < ROWS*64; idx += 256) {
    int ci = idx & 63, row = idx >> 6;
    int g = s0 - 1 + row;
    unsigned short v = 0;
    if (g >= 0 && g < Tin) v = in[(size_t)(b*64 + ci)*Tin + g];
    lB[row*RSB + ci] = (short)v;
  }

  // bias-initialized accumulators (C/D layout)
  f32x16 binit;
  #pragma unroll
  for (int r = 0; r < 16; ++r)
    binit[r] = bias[mt*32 + (r & 3) + 8*(r >> 2) + 4*(L >> 5)];
  f32x16 Ce[G], Co[G];
  #pragma unroll
  for (int nt = 0; nt < G; ++nt) { Ce[nt] = binit; Co[nt] = binit; }

  __syncthreads();

  #pragma unroll
  for (int nt = 0; nt < G; ++nt) {
    const int localn = ng*(32*G) + nt*32 + (L & 31);
    const short* bp = lB + localn*RSB + ((L >> 5) << 3);
    #pragma unroll
    for (int ks = 0; ks < 4; ++ks) {
      bf16x8 Bm = *(const bf16x8*)(bp + ks*16);            // shift -1
      bf16x8 B0 = *(const bf16x8*)(bp + RSB + ks*16);      // shift  0
      bf16x8 Bp = *(const bf16x8*)(bp + 2*RSB + ks*16);    // shift +1
      Ce[nt] = __builtin_amdgcn_mfma_f32_32x32x16_bf16(Af[0][ks], Bm, Ce[nt], 0, 0, 0);
      Ce[nt] = __builtin_amdgcn_mfma_f32_32x32x16_bf16(Af[1][ks], B0, Ce[nt], 0, 0, 0);
      Co[nt] = __builtin_amdgcn_mfma_f32_32x32x16_bf16(Af[2][ks], B0, Co[nt], 0, 0, 0);
      Co[nt] = __builtin_amdgcn_mfma_f32_32x32x16_bf16(Af[3][ks], Bp, Co[nt], 0, 0, 0);
    }
  }

  // store: pack (even,odd) bf16 pair as one dword at out[(b*64+co)*2Tin + 2s]
  unsigned int* outw = (unsigned int*)out;
  #pragma unroll
  for (int nt = 0; nt < G; ++nt) {
    const int sg = s0 + ng*(32*G) + nt*32 + (L & 31);
    if (sg < Tin) {
      #pragma unroll
      for (int r = 0; r < 16; ++r) {
        int co = mt*32 + (r & 3) + 8*(r >> 2) + 4*(L >> 5);
        unsigned int pk = (unsigned int)f2bf(lrelu(Ce[nt][r]))
                        | ((unsigned int)f2bf(lrelu(Co[nt][r])) << 16);
        outw[(size_t)(b*64 + co)*Tin + sg] = pk;
      }
    }
  }
}

// ---------------------------------------------------------------------------
// Oscillator bank: harm[b,t] = sum_o amp*sin(pi*S); O(1) phase from boundary
// table (frac(P/2) f32, fp64-exact). Writes out (runs before nz_final).
// ---------------------------------------------------------------------------
__global__ __launch_bounds__(256) void osc_kernel(
    const float* __restrict__ amp, const float* __restrict__ frq,
    const float* __restrict__ ph, float* __restrict__ out)
{
  __shared__ float al[1024], fq[1024], pl[1024];
  const int b   = blockIdx.y;
  const int T0  = blockIdx.x * 1024;
  const int tid = threadIdx.x;
  for (int i = tid; i < 1024; i += 256) {
    al[i] = amp[b*1024 + i];
    fq[i] = frq[b*1024 + i];
    pl[i] = ph[b*1024 + i];
  }
  __syncthreads();
  #pragma unroll
  for (int j = 0; j < 4; ++j) {
    const int t = T0 + tid + 256*j;
    float acc = 0.f;
    if (t < 256) {
      const float tp = (float)(t + 1) * 0.5f;
      for (int o = 0; o < 32; ++o) {
        float v  = tp * fq[o*32];
        float fr = v - floorf(v);
        acc += al[o*32] * sin_rev(fr);
      }
    } else if (t >= 16128) {
      const float tp = (float)(t - 16127) * 0.5f;
      for (int o = 0; o < 32; ++o) {
        float v  = pl[o*32 + 31] + tp * fq[o*32 + 31];
        float fr = v - floorf(v);
        acc += al[o*32 + 31] * sin_rev(fr);
      }
    } else {
      const int i = (t - 256) >> 9;
      const int m = (t - 256) & 511;
      const float mm = (float)(m + 1);
      const float fa = ((float)m + 0.5f) * (1.f/512.f);
      const float mq = mm * mm * (1.f/1024.f);
      for (int o = 0; o < 32; ++o) {
        float f0 = fq[o*32 + i], f1 = fq[o*32 + i + 1];
        float a0 = al[o*32 + i], a1 = al[o*32 + i + 1];
        float av = a0 + (a1 - a0) * fa;
        float part = mm * f0 + (f1 - f0) * mq;
        float v  = pl[o*32 + i] + part * 0.5f;
        float fr = v - floorf(v);
        acc += av * sin_rev(fr);
      }
    }
    out[b*16384 + t] = acc;
  }
}

// ---------------------------------------------------------------------------
// Final 1x1 conv to 3 rfft coeffs, square, length-4 ortho rfft/irfft filter,
// accumulate into out. y is bf16 now.
// ---------------------------------------------------------------------------
__global__ __launch_bounds__(256) void nz_final_kernel(
    const unsigned short* __restrict__ y, const float* __restrict__ noise,
    const float* __restrict__ w, const float* __restrict__ bias,
    float* __restrict__ out)
{
  __shared__ float wl[192];
  const int tid = threadIdx.x;
  if (tid < 192) {
    int o = tid >> 6, c = tid & 63;
    wl[c*3 + o] = w[tid];
  }
  __syncthreads();
  const int f  = blockIdx.x * 256 + tid;
  const int b  = f >> 12, fr = f & 4095;
  const unsigned short* yb = y + ((size_t)b*64) * 4096 + fr;
  float c0 = bias[0], c1 = bias[1], c2 = bias[2];
  #pragma unroll 4
  for (int c = 0; c < 64; ++c) {
    float yv = bf2f(yb[(size_t)c * 4096]);
    c0 = fmaf(wl[c*3+0], yv, c0);
    c1 = fmaf(wl[c*3+1], yv, c1);
    c2 = fmaf(wl[c*3+2], yv, c2);
  }
  c0 *= c0; c1 *= c1; c2 *= c2;
  const float4 n = *(const float4*)(noise + (size_t)f*4);
  float F0  = c0 * (n.x + n.y + n.z + n.w) * 0.5f;
  float F1r = c1 * (n.x - n.z) * 0.5f;
  float F1i = -(c1 * (n.y - n.w) * 0.5f);
  float F2  = c2 * (n.x - n.y + n.z - n.w) * 0.5f;
  float4 r = *(float4*)(out + (size_t)f*4);
  r.x += 0.5f * (F0 + 2.f*F1r + F2);
  r.y += 0.5f * (F0 - 2.f*F1i - F2);
  r.z += 0.5f * (F0 - 2.f*F1r + F2);
  r.w += 0.5f * (F0 + 2.f*F1i - F2);
  *(float4*)(out + (size_t)f*4) = r;
}

// ---------------------------------------------------------------------------
extern "C" void kernel_launch(void* const* d_in, const int* in_sizes, int n_in,
                              void* d_out, int out_size, void* d_ws, size_t ws_size,
                              hipStream_t stream) {
  (void)in_sizes; (void)n_in; (void)out_size; (void)ws_size;
  const float* x     = (const float*)d_in[0];
  const float* noise = (const float*)d_in[1];
  const float* net_w = (const float*)d_in[2];
  const float* net_b = (const float*)d_in[3];
  const float* fin_w = (const float*)d_in[4];
  const float* fin_b = (const float*)d_in[5];
  const float* amp_w = (const float*)d_in[6];
  const float* amp_b = (const float*)d_in[7];
  const float* frq_w = (const float*)d_in[8];
  const float* frq_b = (const float*)d_in[9];
  const float* nzi_w = (const float*)d_in[10];
  const float* nzi_b = (const float*)d_in[11];
  const float* nzu_w = (const float*)d_in[12];
  const float* nzu_b = (const float*)d_in[13];
  const float* nzf_w = (const float*)d_in[14];
  const float* nzf_b = (const float*)d_in[15];
  float* out = (float*)d_out;

  // workspace (~68 MiB): bufA/bufB bf16 (33.5 MiB each) | wfold bf16 | amp/frq/ph f32
  short* bufA  = (short*)d_ws;
  short* bufB  = bufA + (size_t)64*64*4096;
  short* wfold = bufB + (size_t)64*64*4096;
  float* ampv  = (float*)(wfold + 7*16384);
  float* frqv  = ampv + 65536;
  float* phv   = frqv + 65536;

  fold_w_kernel<<<dim3(448), dim3(256), 0, stream>>>(nzu_w, wfold);

  frontend_kernel<<<dim3(64), dim3(256), 0, stream>>>(
      x, net_w, net_b, fin_w, fin_b, amp_w, amp_b, frq_w, frq_b,
      nzi_w, nzi_b, (unsigned short*)bufA, ampv, frqv, phv);

  // noise stack: y0(T=32,bufA) -> ... -> y7(T=4096,bufB), all bf16 MFMA
  mfma_up_kernel<64>  <<<dim3(1, 64), dim3(256), 0, stream>>>((unsigned short*)bufA, (unsigned short*)bufB, wfold + 0*16384, nzu_b + 0*64, 32);
  mfma_up_kernel<64>  <<<dim3(1, 64), dim3(256), 0, stream>>>((unsigned short*)bufB, (unsigned short*)bufA, wfold + 1*16384, nzu_b + 1*64, 64);
  mfma_up_kernel<128> <<<dim3(1, 64), dim3(256), 0, stream>>>((unsigned short*)bufA, (unsigned short*)bufB, wfold + 2*16384, nzu_b + 2*64, 128);
  mfma_up_kernel<128> <<<dim3(2, 64), dim3(256), 0, stream>>>((unsigned short*)bufB, (unsigned short*)bufA, wfold + 3*16384, nzu_b + 3*64, 256);
  mfma_up_kernel<128> <<<dim3(4, 64), dim3(256), 0, stream>>>((unsigned short*)bufA, (unsigned short*)bufB, wfold + 4*16384, nzu_b + 4*64, 512);
  mfma_up_kernel<128> <<<dim3(8, 64), dim3(256), 0, stream>>>((unsigned short*)bufB, (unsigned short*)bufA, wfold + 5*16384, nzu_b + 5*64, 1024);
  mfma_up_kernel<128> <<<dim3(16,64), dim3(256), 0, stream>>>((unsigned short*)bufA, (unsigned short*)bufB, wfold + 6*16384, nzu_b + 6*64, 2048);

  osc_kernel<<<dim3(16, 64), dim3(256), 0, stream>>>(ampv, frqv, phv, out);
  nz_final_kernel<<<dim3(1024), dim3(256), 0, stream>>>((unsigned short*)bufB, noise, nzf_w, nzf_b, out);
}

// Round 3
// 247.241 us; speedup vs baseline: 2.1695x; 1.0432x over previous
//
#include <hip/hip_runtime.h>
#include <math.h>

// Problem constants
//  B=64, CH=64, T_IN=32, N_OSC=32, BAND=16384, N_NOISE_FRAMES=4096, NOISE_STEP=4
//  N_UP=7, LOWEST_FREQ = 20/11025
#define LOWEST_FREQ_F 0.00181405895691609977f

typedef short bf16x8 __attribute__((ext_vector_type(8)));
typedef float f32x16 __attribute__((ext_vector_type(16)));

__device__ __forceinline__ float lrelu(float x) { return x > 0.f ? x : 0.2f * x; }
__device__ __forceinline__ float sin_rev(float fr) { return __builtin_amdgcn_sinf(fr); }
__device__ __forceinline__ float bf2f(unsigned short u) {
  union { unsigned int i; float f; } x; x.i = ((unsigned int)u) << 16; return x.f;
}
__device__ __forceinline__ unsigned short f2bf(float f) {
  union { float f; unsigned int i; } x; x.f = f;
  unsigned int r = x.i + 0x7FFFu + ((x.i >> 16) & 1u);   // RNE
  return (unsigned short)(r >> 16);
}
__device__ __forceinline__ unsigned int pack2(float a, float b) {
  return (unsigned int)f2bf(a) | ((unsigned int)f2bf(b) << 16);
}

// ---------------------------------------------------------------------------
// prep: transpose frontend weights (net x4 + fin) -> wtF[l][(ci*3+k)][co],
//       amp/frq -> [c][o], nz_init -> [c][o], fold noise conv weights -> bf16
//       wfold[l][pd][co][ci]  (pd: 0=w0, 1=w1+w2, 2=w0+w1, 3=w2)
// ---------------------------------------------------------------------------
__global__ __launch_bounds__(256) void prep_kernel(
    const float* __restrict__ net_w, const float* __restrict__ fin_w,
    const float* __restrict__ amp_w, const float* __restrict__ frq_w,
    const float* __restrict__ nzi_w, const float* __restrict__ nzu_w,
    float* __restrict__ wtF, float* __restrict__ awT, float* __restrict__ fwT,
    float* __restrict__ nzT, short* __restrict__ wfold)
{
  int idx = blockIdx.x * 256 + threadIdx.x;
  if (idx < 61440) {                       // 5 * 12288
    int l = idx / 12288, r = idx - l * 12288;   // r = row*64 + co
    int row = r >> 6, co = r & 63;              // row = ci*3+k
    const float* src = (l < 4) ? (net_w + l * 12288) : fin_w;
    wtF[idx] = src[co * 192 + row];
  } else if (idx < 63488) {                // awT: 2048
    int r = idx - 61440; int c = r >> 5, o = r & 31;
    awT[r] = amp_w[o * 64 + c];
  } else if (idx < 65536) {                // fwT: 2048
    int r = idx - 63488; int c = r >> 5, o = r & 31;
    fwT[r] = frq_w[o * 64 + c];
  } else if (idx < 69632) {                // nzT: 4096
    int r = idx - 65536; int c = r >> 6, o = r & 63;
    nzT[r] = nzi_w[o * 64 + c];
  } else if (idx < 69632 + 114688) {       // wfold: 7*16384
    int r = idx - 69632;
    int l = r >> 14, q = r & 16383;
    int pd = q >> 12, co = (q >> 6) & 63, ci = q & 63;
    const float* wb = nzu_w + l * 12288 + co * 192 + ci * 3;
    float v;
    if      (pd == 0) v = wb[0];
    else if (pd == 1) v = wb[1] + wb[2];
    else if (pd == 2) v = wb[0] + wb[1];
    else              v = wb[2];
    wfold[r] = (short)f2bf(v);
  }
}

// ---------------------------------------------------------------------------
// In-LDS MFMA noise layer (even/odd folded up-conv + leaky).
// tin: rows = sample+1 (halo rows 0 and TIN+1 zero), 64 cols, stride 72 shorts.
// tout: rows = out sample+1 (2*TIN rows + halos), stride 72. Ends with sync.
// v_mfma_f32_32x32x16_bf16 layouts (HW-verified): A[m=L&31][k=(L>>5)*8+j],
// B[k][n=L&31], D col=L&31, row=(r&3)+8*(r>>2)+4*(L>>5).
// ---------------------------------------------------------------------------
template<int TIN>
__device__ __forceinline__ void noise_layer(
    const short* tin, short* tout, const short* __restrict__ wf,
    const float* __restrict__ bias, int tid)
{
  const int L  = tid & 63;
  const int w  = tid >> 6;
  const int mt = w & 1;
  const int ng = w >> 1;

  bf16x8 Af[4][4];
  {
    const short* wb = wf + (mt*32 + (L & 31))*64 + ((L >> 5) << 3);
    #pragma unroll
    for (int pd = 0; pd < 4; ++pd)
      #pragma unroll
      for (int ks = 0; ks < 4; ++ks)
        Af[pd][ks] = *(const bf16x8*)(wb + pd*4096 + ks*16);
  }
  f32x16 binit;
  #pragma unroll
  for (int r = 0; r < 16; ++r)
    binit[r] = bias[mt*32 + (r & 3) + 8*(r >> 2) + 4*(L >> 5)];

  // zero halo rows of output tile
  if (tid < 64) { tout[tid] = 0; tout[(2*TIN + 1)*72 + tid] = 0; }

  constexpr int TOT = TIN / 32;          // n-tiles total
  constexpr int NPG = (TOT + 1) / 2;     // n-tiles per n-group
  #pragma unroll
  for (int nt = 0; nt < NPG; ++nt) {
    int ntile = ng*NPG + nt;
    if (ntile < TOT) {
      int s = ntile*32 + (L & 31);
      const short* bp = tin + s*72 + ((L >> 5) << 3);   // row s = sample s-1
      f32x16 Ce = binit, Co = binit;
      #pragma unroll
      for (int ks = 0; ks < 4; ++ks) {
        bf16x8 Bm = *(const bf16x8*)(bp + ks*16);
        bf16x8 B0 = *(const bf16x8*)(bp + 72 + ks*16);
        bf16x8 Bp = *(const bf16x8*)(bp + 144 + ks*16);
        Ce = __builtin_amdgcn_mfma_f32_32x32x16_bf16(Af[0][ks], Bm, Ce, 0, 0, 0);
        Ce = __builtin_amdgcn_mfma_f32_32x32x16_bf16(Af[1][ks], B0, Ce, 0, 0, 0);
        Co = __builtin_amdgcn_mfma_f32_32x32x16_bf16(Af[2][ks], B0, Co, 0, 0, 0);
        Co = __builtin_amdgcn_mfma_f32_32x32x16_bf16(Af[3][ks], Bp, Co, 0, 0, 0);
      }
      // store: even t=2s -> row 2s+1, odd t=2s+1 -> row 2s+2; 4-co packs (8B)
      #pragma unroll
      for (int q4 = 0; q4 < 4; ++q4) {
        int co0 = mt*32 + 8*q4 + 4*(L >> 5);
        uint2 ve, vo;
        ve.x = pack2(lrelu(Ce[4*q4+0]), lrelu(Ce[4*q4+1]));
        ve.y = pack2(lrelu(Ce[4*q4+2]), lrelu(Ce[4*q4+3]));
        vo.x = pack2(lrelu(Co[4*q4+0]), lrelu(Co[4*q4+1]));
        vo.y = pack2(lrelu(Co[4*q4+2]), lrelu(Co[4*q4+3]));
        *(uint2*)&tout[(2*s + 1)*72 + co0] = ve;
        *(uint2*)&tout[(2*s + 2)*72 + co0] = vo;
      }
    }
  }
  __syncthreads();
}

// ---------------------------------------------------------------------------
// Fused frontend: f32 conv stack (register-double-buffered weights), nz_init,
// amp/freq projections, fp64 phase boundaries, then noise layers 0..3 in LDS
// (T 32->512), writing y4 bf16 [b][t][co] to global. One block per batch.
// ---------------------------------------------------------------------------
__global__ __launch_bounds__(256) void frontend_fused(
    const float* __restrict__ x, const float* __restrict__ wtF,
    const float* __restrict__ net_b, const float* __restrict__ fin_b,
    const float* __restrict__ awT, const float* __restrict__ amp_b,
    const float* __restrict__ fwT, const float* __restrict__ frq_b,
    const float* __restrict__ nzT, const float* __restrict__ nzi_b,
    const short* __restrict__ wfold, const float* __restrict__ nzu_b,
    unsigned short* __restrict__ y4, float* __restrict__ amp_o,
    float* __restrict__ frq_o, float* __restrict__ ph_o)
{
  // arena: [tileA cap 514 rows: 74016 B][tileB cap 258 rows: 37152 B]
  //        [za 9216][zb 9216][fl 4224]  = 133824 B. wbuf (49152 B) overlays
  //        tileA region (dead before tiles are used).
  __shared__ __align__(16) char arena[133824];
  float* wbuf  = (float*)arena;
  short* tileA = (short*)arena;
  short* tileB = (short*)(arena + 74016);
  float* za    = (float*)(arena + 111168);
  float* zb    = (float*)(arena + 120384);
  float* fl    = (float*)(arena + 129600);

  const int b   = blockIdx.x;
  const int tid = threadIdx.x;
  const int co  = tid & 63;
  const int q   = tid >> 6;

  // stage layer-0 weights (regs) + input
  float4 pf[12];
  #pragma unroll
  for (int i = 0; i < 12; ++i) pf[i] = ((const float4*)wtF)[tid + i*256];
  for (int idx = tid; idx < 2048; idx += 256) {
    int t = idx >> 6, c = idx & 63;
    za[c*36 + t + 1] = x[b*2048 + idx];
  }
  if (tid < 64) {
    za[tid*36] = 0.f; za[tid*36 + 33] = 0.f;
    zb[tid*36] = 0.f; zb[tid*36 + 33] = 0.f;
  }
  #pragma unroll
  for (int i = 0; i < 12; ++i) ((float4*)wbuf)[tid + i*256] = pf[i];
  __syncthreads();

  float* pa = za;
  float* pb = zb;
  for (int l = 0; l < 5; ++l) {
    if (l < 4) {   // prefetch next layer's weights into registers
      #pragma unroll
      for (int i = 0; i < 12; ++i)
        pf[i] = ((const float4*)wtF)[(l+1)*3072 + tid + i*256];
    }
    float acc[8];
    {
      float bv = (l < 4) ? net_b[l*64 + co] : fin_b[co];
      #pragma unroll
      for (int j = 0; j < 8; ++j) acc[j] = bv;
    }
    for (int ci = 0; ci < 64; ++ci) {
      const float* row = pa + ci*36 + q*8;
      float rr[12];
      #pragma unroll
      for (int i = 0; i < 3; ++i) {
        float4 v = *(const float4*)(row + 4*i);
        rr[4*i+0]=v.x; rr[4*i+1]=v.y; rr[4*i+2]=v.z; rr[4*i+3]=v.w;
      }
      float w0 = wbuf[(ci*3+0)*64 + co];
      float w1 = wbuf[(ci*3+1)*64 + co];
      float w2 = wbuf[(ci*3+2)*64 + co];
      #pragma unroll
      for (int j = 0; j < 8; ++j) {
        acc[j] = fmaf(w0, rr[j],   acc[j]);
        acc[j] = fmaf(w1, rr[j+1], acc[j]);
        acc[j] = fmaf(w2, rr[j+2], acc[j]);
      }
    }
    const bool act = (l < 4);
    #pragma unroll
    for (int j = 0; j < 8; ++j) {
      float v = acc[j];
      pb[co*36 + q*8 + j + 1] = act ? lrelu(v) : v;
    }
    __syncthreads();
    if (l < 4) {
      #pragma unroll
      for (int i = 0; i < 12; ++i) ((float4*)wbuf)[tid + i*256] = pf[i];
      __syncthreads();
    }
    float* tp = pa; pa = pb; pb = tp;
  }
  const float* zf = pa;  // final z, 64ch x 32t (+pads)

  // ---- y0 = nz_init 1x1 conv -> bf16 into tileA rows t+1 ----
  {
    float acc[8];
    float bv = nzi_b[co];
    #pragma unroll
    for (int j = 0; j < 8; ++j) acc[j] = bv;
    #pragma unroll 8
    for (int c = 0; c < 64; ++c) {
      float wv = nzT[c*64 + co];
      const float* rw = zf + c*36 + q*8 + 1;
      #pragma unroll
      for (int j = 0; j < 8; ++j) acc[j] = fmaf(wv, rw[j], acc[j]);
    }
    #pragma unroll
    for (int j = 0; j < 8; ++j)
      tileA[(q*8 + j + 1)*72 + co] = (short)f2bf(acc[j]);
  }
  if (tid < 64) { tileA[tid] = 0; tileA[33*72 + tid] = 0; }

  // ---- amp / freq projections (weights direct from global, transposed) ----
  #pragma unroll
  for (int tt = 0; tt < 4; ++tt) {
    int task = tid + 256*tt;
    int o = task & 31, t = task >> 5;
    float aa = amp_b[o], ff = frq_b[o];
    #pragma unroll 8
    for (int c = 0; c < 64; ++c) {
      float zv = zf[c*36 + t + 1];
      aa = fmaf(awT[c*32 + o], zv, aa);
      ff = fmaf(fwT[c*32 + o], zv, ff);
    }
    aa = fabsf(aa);
    float sg = 1.f / (1.f + expf(-ff));
    float fq = LOWEST_FREQ_F + sg * (1.f - LOWEST_FREQ_F);
    amp_o[b*1024 + o*32 + t] = aa;
    frq_o[b*1024 + o*32 + t] = fq;
    fl[o*33 + t] = fq;
  }
  __syncthreads();

  // ---- fp64 phase boundary prefix: store frac(P[i]/2) ----
  if (tid < 32) {
    const int o = tid;
    double P = 256.0 * (double)fl[o*33];
    double h = P * 0.5;
    ph_o[b*1024 + o*32] = (float)(h - floor(h));
    for (int i = 1; i < 32; ++i) {
      P += 256.0 * ((double)fl[o*33 + i - 1] + (double)fl[o*33 + i]);
      h = P * 0.5;
      ph_o[b*1024 + o*32 + i] = (float)(h - floor(h));
    }
  }

  // ---- noise layers 0..3 in LDS: T 32 -> 64 -> 128 -> 256 -> 512 ----
  noise_layer<32> (tileA, tileB, wfold + 0*16384, nzu_b + 0*64, tid);
  noise_layer<64> (tileB, tileA, wfold + 1*16384, nzu_b + 1*64, tid);
  noise_layer<128>(tileA, tileB, wfold + 2*16384, nzu_b + 2*64, tid);
  noise_layer<256>(tileB, tileA, wfold + 3*16384, nzu_b + 3*64, tid);

  // write y4 [b][t][co] (contiguous b128 copies)
  unsigned short* yb = y4 + (size_t)b * 32768;
  for (int c = tid; c < 4096; c += 256) {
    int row = c >> 3, pos = (c & 7) << 3;
    *(bf16x8*)(yb + c*8) = *(const bf16x8*)&tileA[(row + 1)*72 + pos];
  }
}

// ---------------------------------------------------------------------------
// Global-to-global MFMA up-conv layer, [b][t][co] layout (coalesced staging).
// ---------------------------------------------------------------------------
template<int STILE>
__global__ __launch_bounds__(256) void mfma_up_t(
    const unsigned short* __restrict__ in, unsigned short* __restrict__ out,
    const short* __restrict__ wf, const float* __restrict__ bias, int Tin)
{
  constexpr int ROWS = STILE + 2;
  constexpr int G    = STILE / 64;
  __shared__ __align__(16) short lB[ROWS * 72];

  const int b   = blockIdx.y;
  const int s0  = blockIdx.x * STILE;
  const int tid = threadIdx.x;
  const int L   = tid & 63;
  const int w   = tid >> 6;
  const int mt  = w & 1;
  const int ng  = w >> 1;

  bf16x8 Af[4][4];
  {
    const short* wb = wf + (mt*32 + (L & 31))*64 + ((L >> 5) << 3);
    #pragma unroll
    for (int pd = 0; pd < 4; ++pd)
      #pragma unroll
      for (int ks = 0; ks < 4; ++ks)
        Af[pd][ks] = *(const bf16x8*)(wb + pd*4096 + ks*16);
  }

  // stage rows s0-1 .. s0+STILE (16B chunks, coalesced)
  const unsigned short* inb = in + (size_t)b * Tin * 64;
  for (int c = tid; c < ROWS*8; c += 256) {
    int row = c >> 3, pos = (c & 7) << 3;
    int g = s0 - 1 + row;
    bf16x8 v = {0,0,0,0,0,0,0,0};
    if (g >= 0 && g < Tin) v = *(const bf16x8*)(inb + (size_t)g*64 + pos);
    *(bf16x8*)&lB[row*72 + pos] = v;
  }

  f32x16 binit;
  #pragma unroll
  for (int r = 0; r < 16; ++r)
    binit[r] = bias[mt*32 + (r & 3) + 8*(r >> 2) + 4*(L >> 5)];

  __syncthreads();

  unsigned short* outb = out + (size_t)b * (2*Tin) * 64;
  #pragma unroll
  for (int nt = 0; nt < G; ++nt) {
    int s_loc = ng*(32*G) + nt*32 + (L & 31);
    const short* bp = lB + s_loc*72 + ((L >> 5) << 3);
    f32x16 Ce = binit, Co = binit;
    #pragma unroll
    for (int ks = 0; ks < 4; ++ks) {
      bf16x8 Bm = *(const bf16x8*)(bp + ks*16);
      bf16x8 B0 = *(const bf16x8*)(bp + 72 + ks*16);
      bf16x8 Bp = *(const bf16x8*)(bp + 144 + ks*16);
      Ce = __builtin_amdgcn_mfma_f32_32x32x16_bf16(Af[0][ks], Bm, Ce, 0, 0, 0);
      Ce = __builtin_amdgcn_mfma_f32_32x32x16_bf16(Af[1][ks], B0, Ce, 0, 0, 0);
      Co = __builtin_amdgcn_mfma_f32_32x32x16_bf16(Af[2][ks], B0, Co, 0, 0, 0);
      Co = __builtin_amdgcn_mfma_f32_32x32x16_bf16(Af[3][ks], Bp, Co, 0, 0, 0);
    }
    int t0 = (s0 + s_loc) * 2;
    #pragma unroll
    for (int q4 = 0; q4 < 4; ++q4) {
      int co0 = mt*32 + 8*q4 + 4*(L >> 5);
      uint2 ve, vo;
      ve.x = pack2(lrelu(Ce[4*q4+0]), lrelu(Ce[4*q4+1]));
      ve.y = pack2(lrelu(Ce[4*q4+2]), lrelu(Ce[4*q4+3]));
      vo.x = pack2(lrelu(Co[4*q4+0]), lrelu(Co[4*q4+1]));
      vo.y = pack2(lrelu(Co[4*q4+2]), lrelu(Co[4*q4+3]));
      *(uint2*)(outb + (size_t)t0*64 + co0)       = ve;
      *(uint2*)(outb + (size_t)(t0+1)*64 + co0)   = vo;
    }
  }
}

// ---------------------------------------------------------------------------
// Oscillator-bank sample (O(1) phase from fp64-exact boundary table)
// ---------------------------------------------------------------------------
__device__ __forceinline__ float osc_sample(int t, const float* al,
                                            const float* fq, const float* pl)
{
  float acc = 0.f;
  if (t < 256) {
    const float tp = (float)(t + 1) * 0.5f;
    #pragma unroll 4
    for (int o = 0; o < 32; ++o) {
      float v  = tp * fq[o*32];
      float fr = v - floorf(v);
      acc += al[o*32] * sin_rev(fr);
    }
  } else if (t >= 16128) {
    const float tp = (float)(t - 16127) * 0.5f;
    #pragma unroll 4
    for (int o = 0; o < 32; ++o) {
      float v  = pl[o*32 + 31] + tp * fq[o*32 + 31];
      float fr = v - floorf(v);
      acc += al[o*32 + 31] * sin_rev(fr);
    }
  } else {
    const int i = (t - 256) >> 9;
    const int m = (t - 256) & 511;
    const float mm = (float)(m + 1);
    const float fa = ((float)m + 0.5f) * (1.f/512.f);
    const float mq = mm * mm * (1.f/1024.f);
    #pragma unroll 4
    for (int o = 0; o < 32; ++o) {
      float f0 = fq[o*32 + i], f1 = fq[o*32 + i + 1];
      float a0 = al[o*32 + i], a1 = al[o*32 + i + 1];
      float av = a0 + (a1 - a0) * fa;
      float part = mm * f0 + (f1 - f0) * mq;
      float v  = pl[o*32 + i] + part * 0.5f;
      float fr = v - floorf(v);
      acc += av * sin_rev(fr);
    }
  }
  return acc;
}

// ---------------------------------------------------------------------------
// Final fused kernel: last up-conv layer (Tin=2048 -> 4096, in LDS) +
// nz_final 1x1 conv to 3 coeffs + squared + length-4 ortho rfft/irfft filter
// + oscillator bank. Writes out directly (no RMW, y7 never in global).
// ---------------------------------------------------------------------------
__global__ __launch_bounds__(256) void final_fused(
    const unsigned short* __restrict__ in,    // y6 [b][t][co], Tin=2048
    const short* __restrict__ wf, const float* __restrict__ bias,
    const float* __restrict__ nzf_w, const float* __restrict__ nzf_b,
    const float* __restrict__ noise,
    const float* __restrict__ amp, const float* __restrict__ frq,
    const float* __restrict__ ph, float* __restrict__ out)
{
  constexpr int STILE = 128, Tin = 2048, ROWS = STILE + 2, G = STILE / 64;
  __shared__ __align__(16) short lB[ROWS * 72];     // 18720 B
  __shared__ __align__(16) short yT[256 * 72];      // 36864 B
  __shared__ float al[1024], fqv[1024], pl[1024];   // 12288 B
  __shared__ float wl[192];

  const int b   = blockIdx.y;
  const int s0  = blockIdx.x * STILE;
  const int tid = threadIdx.x;
  const int L   = tid & 63;
  const int w   = tid >> 6;
  const int mt  = w & 1;
  const int ng  = w >> 1;

  // stage osc tables + nz_final weights
  for (int i = tid; i < 1024; i += 256) {
    al[i]  = amp[b*1024 + i];
    fqv[i] = frq[b*1024 + i];
    pl[i]  = ph[b*1024 + i];
  }
  if (tid < 192) { int o = tid >> 6, c = tid & 63; wl[c*3 + o] = nzf_w[tid]; }

  bf16x8 Af[4][4];
  {
    const short* wb = wf + (mt*32 + (L & 31))*64 + ((L >> 5) << 3);
    #pragma unroll
    for (int pd = 0; pd < 4; ++pd)
      #pragma unroll
      for (int ks = 0; ks < 4; ++ks)
        Af[pd][ks] = *(const bf16x8*)(wb + pd*4096 + ks*16);
  }

  const unsigned short* inb = in + (size_t)b * Tin * 64;
  for (int c = tid; c < ROWS*8; c += 256) {
    int row = c >> 3, pos = (c & 7) << 3;
    int g = s0 - 1 + row;
    bf16x8 v = {0,0,0,0,0,0,0,0};
    if (g >= 0 && g < Tin) v = *(const bf16x8*)(inb + (size_t)g*64 + pos);
    *(bf16x8*)&lB[row*72 + pos] = v;
  }

  f32x16 binit;
  #pragma unroll
  for (int r = 0; r < 16; ++r)
    binit[r] = bias[mt*32 + (r & 3) + 8*(r >> 2) + 4*(L >> 5)];

  __syncthreads();

  #pragma unroll
  for (int nt = 0; nt < G; ++nt) {
    int s_loc = ng*(32*G) + nt*32 + (L & 31);
    const short* bp = lB + s_loc*72 + ((L >> 5) << 3);
    f32x16 Ce = binit, Co = binit;
    #pragma unroll
    for (int ks = 0; ks < 4; ++ks) {
      bf16x8 Bm = *(const bf16x8*)(bp + ks*16);
      bf16x8 B0 = *(const bf16x8*)(bp + 72 + ks*16);
      bf16x8 Bp = *(const bf16x8*)(bp + 144 + ks*16);
      Ce = __builtin_amdgcn_mfma_f32_32x32x16_bf16(Af[0][ks], Bm, Ce, 0, 0, 0);
      Ce = __builtin_amdgcn_mfma_f32_32x32x16_bf16(Af[1][ks], B0, Ce, 0, 0, 0);
      Co = __builtin_amdgcn_mfma_f32_32x32x16_bf16(Af[2][ks], B0, Co, 0, 0, 0);
      Co = __builtin_amdgcn_mfma_f32_32x32x16_bf16(Af[3][ks], Bp, Co, 0, 0, 0);
    }
    // store y7 tile rows (local t = 2*s_loc, 2*s_loc+1)
    #pragma unroll
    for (int q4 = 0; q4 < 4; ++q4) {
      int co0 = mt*32 + 8*q4 + 4*(L >> 5);
      uint2 ve, vo;
      ve.x = pack2(lrelu(Ce[4*q4+0]), lrelu(Ce[4*q4+1]));
      ve.y = pack2(lrelu(Ce[4*q4+2]), lrelu(Ce[4*q4+3]));
      vo.x = pack2(lrelu(Co[4*q4+0]), lrelu(Co[4*q4+1]));
      vo.y = pack2(lrelu(Co[4*q4+2]), lrelu(Co[4*q4+3]));
      int tl = 2*(s_loc - s0*0) - 0;  // s_loc is block-local already
      (void)tl;
      *(uint2*)&yT[(2*(s_loc - 0))*72 + co0]     = ve;
      *(uint2*)&yT[(2*(s_loc - 0) + 1)*72 + co0] = vo;
    }
  }
  __syncthreads();

  // epilogue: thread <-> one frame (local t = tid, global frame fb)
  {
    const short* yr = &yT[tid * 72];
    float c0 = nzf_b[0], c1 = nzf_b[1], c2 = nzf_b[2];
    #pragma unroll
    for (int c8 = 0; c8 < 8; ++c8) {
      bf16x8 v = *(const bf16x8*)(yr + c8*8);
      #pragma unroll
      for (int j = 0; j < 8; ++j) {
        float yv = bf2f((unsigned short)v[j]);
        int c = c8*8 + j;
        c0 = fmaf(wl[c*3+0], yv, c0);
        c1 = fmaf(wl[c*3+1], yv, c1);
        c2 = fmaf(wl[c*3+2], yv, c2);
      }
    }
    c0 *= c0; c1 *= c1; c2 *= c2;

    const int fb = 2*s0 + tid;                 // frame in [0,4096)
    const float4 n = *(const float4*)(noise + ((size_t)b*4096 + fb)*4);
    float F0  = c0 * (n.x + n.y + n.z + n.w) * 0.5f;
    float F1r = c1 * (n.x - n.z) * 0.5f;
    float F1i = -(c1 * (n.y - n.w) * 0.5f);
    float F2  = c2 * (n.x - n.y + n.z - n.w) * 0.5f;
    float nz0 = 0.5f * (F0 + 2.f*F1r + F2);
    float nz1 = 0.5f * (F0 - 2.f*F1i - F2);
    float nz2 = 0.5f * (F0 - 2.f*F1r + F2);
    float nz3 = 0.5f * (F0 + 2.f*F1i - F2);

    const int t0 = fb * 4;
    float4 res;
    res.x = osc_sample(t0 + 0, al, fqv, pl) + nz0;
    res.y = osc_sample(t0 + 1, al, fqv, pl) + nz1;
    res.z = osc_sample(t0 + 2, al, fqv, pl) + nz2;
    res.w = osc_sample(t0 + 3, al, fqv, pl) + nz3;
    *(float4*)(out + ((size_t)b*4096 + fb)*4) = res;
  }
}

// ---------------------------------------------------------------------------
extern "C" void kernel_launch(void* const* d_in, const int* in_sizes, int n_in,
                              void* d_out, int out_size, void* d_ws, size_t ws_size,
                              hipStream_t stream) {
  (void)in_sizes; (void)n_in; (void)out_size; (void)ws_size;
  const float* x     = (const float*)d_in[0];
  const float* noise = (const float*)d_in[1];
  const float* net_w = (const float*)d_in[2];
  const float* net_b = (const float*)d_in[3];
  const float* fin_w = (const float*)d_in[4];
  const float* fin_b = (const float*)d_in[5];
  const float* amp_w = (const float*)d_in[6];
  const float* amp_b = (const float*)d_in[7];
  const float* frq_w = (const float*)d_in[8];
  const float* frq_b = (const float*)d_in[9];
  const float* nzi_w = (const float*)d_in[10];
  const float* nzi_b = (const float*)d_in[11];
  const float* nzu_w = (const float*)d_in[12];
  const float* nzu_b = (const float*)d_in[13];
  const float* nzf_w = (const float*)d_in[14];
  const float* nzf_b = (const float*)d_in[15];
  float* out = (float*)d_out;

  // workspace layout (~31 MiB)
  short* y4    = (short*)d_ws;                       // 64*512*64
  short* y5    = y4 + (size_t)64*512*64;             // 64*1024*64
  short* y6    = y5 + (size_t)64*1024*64;            // 64*2048*64
  short* wfold = y6 + (size_t)64*2048*64;            // 7*16384
  float* wtF   = (float*)(wfold + 7*16384);          // 5*12288
  float* awT   = wtF + 61440;                        // 2048
  float* fwT   = awT + 2048;                         // 2048
  float* nzT   = fwT + 2048;                         // 4096
  float* ampv  = nzT + 4096;                         // 65536
  float* frqv  = ampv + 65536;
  float* phv   = frqv + 65536;

  prep_kernel<<<dim3(720), dim3(256), 0, stream>>>(
      net_w, fin_w, amp_w, frq_w, nzi_w, nzu_w, wtF, awT, fwT, nzT, wfold);

  frontend_fused<<<dim3(64), dim3(256), 0, stream>>>(
      x, wtF, net_b, fin_b, awT, amp_b, fwT, frq_b, nzT, nzi_b,
      wfold, nzu_b, (unsigned short*)y4, ampv, frqv, phv);

  mfma_up_t<128><<<dim3(4, 64), dim3(256), 0, stream>>>(
      (unsigned short*)y4, (unsigned short*)y5, wfold + 4*16384, nzu_b + 4*64, 512);
  mfma_up_t<128><<<dim3(8, 64), dim3(256), 0, stream>>>(
      (unsigned short*)y5, (unsigned short*)y6, wfold + 5*16384, nzu_b + 5*64, 1024);

  final_fused<<<dim3(16, 64), dim3(256), 0, stream>>>(
      (unsigned short*)y6, wfold + 6*16384, nzu_b + 6*64,
      nzf_w, nzf_b, noise, ampv, frqv, phv, out);
}

// Round 4
// 219.268 us; speedup vs baseline: 2.4463x; 1.1276x over previous
//
#include <hip/hip_runtime.h>
#include <math.h>

// Problem constants
//  B=64, CH=64, T_IN=32, N_OSC=32, BAND=16384, N_NOISE_FRAMES=4096, NOISE_STEP=4
//  N_UP=7, LOWEST_FREQ = 20/11025
#define LOWEST_FREQ_F 0.00181405895691609977f

typedef short bf16x8 __attribute__((ext_vector_type(8)));
typedef float f32x16 __attribute__((ext_vector_type(16)));

__device__ __forceinline__ float lrelu(float x) { return x > 0.f ? x : 0.2f * x; }
__device__ __forceinline__ float sin_rev(float fr) { return __builtin_amdgcn_sinf(fr); }
__device__ __forceinline__ float bf2f(unsigned short u) {
  union { unsigned int i; float f; } x; x.i = ((unsigned int)u) << 16; return x.f;
}
__device__ __forceinline__ unsigned short f2bf(float f) {
  union { float f; unsigned int i; } x; x.f = f;
  unsigned int r = x.i + 0x7FFFu + ((x.i >> 16) & 1u);   // RNE
  return (unsigned short)(r >> 16);
}
__device__ __forceinline__ unsigned int pack2(float a, float b) {
  return (unsigned int)f2bf(a) | ((unsigned int)f2bf(b) << 16);
}

// ---------------------------------------------------------------------------
// prep: transpose frontend weights (net x4 + fin) -> wtF[l][(ci*3+k)][co],
//       amp/frq -> [c][o], nz_init -> [c][o], fold noise conv weights -> bf16
//       wfold[l][pd][co][ci]  (pd: 0=w0, 1=w1+w2, 2=w0+w1, 3=w2)
// ---------------------------------------------------------------------------
__global__ __launch_bounds__(256) void prep_kernel(
    const float* __restrict__ net_w, const float* __restrict__ fin_w,
    const float* __restrict__ amp_w, const float* __restrict__ frq_w,
    const float* __restrict__ nzi_w, const float* __restrict__ nzu_w,
    float* __restrict__ wtF, float* __restrict__ awT, float* __restrict__ fwT,
    float* __restrict__ nzT, short* __restrict__ wfold)
{
  int idx = blockIdx.x * 256 + threadIdx.x;
  if (idx < 61440) {                       // 5 * 12288
    int l = idx / 12288, r = idx - l * 12288;   // r = row*64 + co
    int row = r >> 6, co = r & 63;              // row = ci*3+k
    const float* src = (l < 4) ? (net_w + l * 12288) : fin_w;
    wtF[idx] = src[co * 192 + row];
  } else if (idx < 63488) {                // awT: 2048
    int r = idx - 61440; int c = r >> 5, o = r & 31;
    awT[r] = amp_w[o * 64 + c];
  } else if (idx < 65536) {                // fwT: 2048
    int r = idx - 63488; int c = r >> 5, o = r & 31;
    fwT[r] = frq_w[o * 64 + c];
  } else if (idx < 69632) {                // nzT: 4096
    int r = idx - 65536; int c = r >> 6, o = r & 63;
    nzT[r] = nzi_w[o * 64 + c];
  } else if (idx < 69632 + 114688) {       // wfold: 7*16384
    int r = idx - 69632;
    int l = r >> 14, q = r & 16383;
    int pd = q >> 12, co = (q >> 6) & 63, ci = q & 63;
    const float* wb = nzu_w + l * 12288 + co * 192 + ci * 3;
    float v;
    if      (pd == 0) v = wb[0];
    else if (pd == 1) v = wb[1] + wb[2];
    else if (pd == 2) v = wb[0] + wb[1];
    else              v = wb[2];
    wfold[r] = (short)f2bf(v);
  }
}

// ---------------------------------------------------------------------------
// In-LDS MFMA noise layer (even/odd folded up-conv + leaky), 8-wave version.
// tin rows = sample+1 (halos 0 and TIN+1 zero), 64 cols, stride 72 shorts.
// Ends with __syncthreads.
// v_mfma_f32_32x32x16_bf16 (HW-verified): A[m=L&31][k=(L>>5)*8+j],
// B[k][n=L&31], D col=L&31, row=(r&3)+8*(r>>2)+4*(L>>5).
// ---------------------------------------------------------------------------
template<int TIN>
__device__ __forceinline__ void noise_layer(
    const short* tin, short* tout, const short* __restrict__ wf,
    const float* __restrict__ bias, int tid)
{
  const int L  = tid & 63;
  const int w  = tid >> 6;
  const int mt = w & 1;
  const int ng = w >> 1;          // 0..3

  bf16x8 Af[4][4];
  {
    const short* wb = wf + (mt*32 + (L & 31))*64 + ((L >> 5) << 3);
    #pragma unroll
    for (int pd = 0; pd < 4; ++pd)
      #pragma unroll
      for (int ks = 0; ks < 4; ++ks)
        Af[pd][ks] = *(const bf16x8*)(wb + pd*4096 + ks*16);
  }
  f32x16 binit;
  #pragma unroll
  for (int r = 0; r < 16; ++r)
    binit[r] = bias[mt*32 + (r & 3) + 8*(r >> 2) + 4*(L >> 5)];

  if (tid < 64) { tout[tid] = 0; tout[(2*TIN + 1)*72 + tid] = 0; }

  constexpr int TOT = TIN / 32;          // n-tiles total
  constexpr int NPG = (TOT + 3) / 4;     // n-tiles per ng group
  #pragma unroll
  for (int nt = 0; nt < NPG; ++nt) {
    int ntile = ng*NPG + nt;
    if (ntile < TOT) {
      int s = ntile*32 + (L & 31);
      const short* bp = tin + s*72 + ((L >> 5) << 3);   // row s = sample s-1
      f32x16 Ce = binit, Co = binit;
      #pragma unroll
      for (int ks = 0; ks < 4; ++ks) {
        bf16x8 Bm = *(const bf16x8*)(bp + ks*16);
        bf16x8 B0 = *(const bf16x8*)(bp + 72 + ks*16);
        bf16x8 Bp = *(const bf16x8*)(bp + 144 + ks*16);
        Ce = __builtin_amdgcn_mfma_f32_32x32x16_bf16(Af[0][ks], Bm, Ce, 0, 0, 0);
        Ce = __builtin_amdgcn_mfma_f32_32x32x16_bf16(Af[1][ks], B0, Ce, 0, 0, 0);
        Co = __builtin_amdgcn_mfma_f32_32x32x16_bf16(Af[2][ks], B0, Co, 0, 0, 0);
        Co = __builtin_amdgcn_mfma_f32_32x32x16_bf16(Af[3][ks], Bp, Co, 0, 0, 0);
      }
      #pragma unroll
      for (int q4 = 0; q4 < 4; ++q4) {
        int co0 = mt*32 + 8*q4 + 4*(L >> 5);
        uint2 ve, vo;
        ve.x = pack2(lrelu(Ce[4*q4+0]), lrelu(Ce[4*q4+1]));
        ve.y = pack2(lrelu(Ce[4*q4+2]), lrelu(Ce[4*q4+3]));
        vo.x = pack2(lrelu(Co[4*q4+0]), lrelu(Co[4*q4+1]));
        vo.y = pack2(lrelu(Co[4*q4+2]), lrelu(Co[4*q4+3]));
        *(uint2*)&tout[(2*s + 1)*72 + co0] = ve;
        *(uint2*)&tout[(2*s + 2)*72 + co0] = vo;
      }
    }
  }
  __syncthreads();
}

// ---------------------------------------------------------------------------
// z_front: 512 threads/block, one block per batch.
// f32 conv stack (each thread 4 samples, register-prefetched weights),
// nz_init -> y0 (bf16 tile), amp/freq from LDS-staged weights, fp64 phase
// boundaries, noise layers 0..2 in LDS (T 32->256), write y3 [b][t][co].
// ---------------------------------------------------------------------------
__global__ __launch_bounds__(512) void z_front(
    const float* __restrict__ x, const float* __restrict__ wtF,
    const float* __restrict__ net_b, const float* __restrict__ fin_b,
    const float* __restrict__ awT, const float* __restrict__ amp_b,
    const float* __restrict__ fwT, const float* __restrict__ frq_b,
    const float* __restrict__ nzT, const float* __restrict__ nzi_b,
    const short* __restrict__ wfold, const float* __restrict__ nzu_b,
    unsigned short* __restrict__ y3, float* __restrict__ amp_o,
    float* __restrict__ frq_o, float* __restrict__ ph_o)
{
  // arena: [tileB 258x72sh = 37152 | tileA 130x72sh = 18720]  (wbuf 12288 f32
  //        = 49152 B overlays tiles; dead before tiles used)
  //        za 9216 | zb 9216 | awL 8192 | fwL 8192 | nzL 16384 | fl 4224
  __shared__ __align__(16) char arena[111296];
  short* tileB = (short*)arena;
  short* tileA = (short*)(arena + 37152);
  float* wbuf  = (float*)arena;
  float* za    = (float*)(arena + 55872);
  float* zb    = (float*)(arena + 65088);
  float* awL   = (float*)(arena + 74304);
  float* fwL   = (float*)(arena + 82496);
  float* nzL   = (float*)(arena + 90688);
  float* fl    = (float*)(arena + 107072);

  const int b   = blockIdx.x;
  const int tid = threadIdx.x;
  const int co  = tid & 63;
  const int q   = tid >> 6;   // 0..7, fixed per wave

  // stage layer-0 weights (regs) + input + small weight tables
  float4 pf[6];
  #pragma unroll
  for (int i = 0; i < 6; ++i) pf[i] = ((const float4*)wtF)[tid + i*512];
  for (int idx = tid; idx < 2048; idx += 512) {
    int t = idx >> 6, c = idx & 63;
    za[c*36 + t + 1] = x[b*2048 + idx];
  }
  if (tid < 64) {
    za[tid*36] = 0.f; za[tid*36 + 33] = 0.f;
    zb[tid*36] = 0.f; zb[tid*36 + 33] = 0.f;
  }
  ((float4*)awL)[tid & 511] = ((const float4*)awT)[tid & 511];   // 512 x f4
  ((float4*)fwL)[tid & 511] = ((const float4*)fwT)[tid & 511];
  ((float4*)nzL)[tid]       = ((const float4*)nzT)[tid];
  ((float4*)nzL)[tid + 512] = ((const float4*)nzT)[tid + 512];
  #pragma unroll
  for (int i = 0; i < 6; ++i) ((float4*)wbuf)[tid + i*512] = pf[i];
  __syncthreads();

  float* pa = za;
  float* pb = zb;
  for (int l = 0; l < 5; ++l) {
    if (l < 4) {   // prefetch next layer's weights into registers
      #pragma unroll
      for (int i = 0; i < 6; ++i)
        pf[i] = ((const float4*)wtF)[(l+1)*3072 + tid + i*512];
    }
    float acc[4];
    {
      float bv = (l < 4) ? net_b[l*64 + co] : fin_b[co];
      #pragma unroll
      for (int j = 0; j < 4; ++j) acc[j] = bv;
    }
    for (int ci = 0; ci < 64; ++ci) {
      const float* row = pa + ci*36 + q*4;
      float4 v0 = *(const float4*)(row);
      float4 v1 = *(const float4*)(row + 4);
      float rr[8] = {v0.x, v0.y, v0.z, v0.w, v1.x, v1.y, v1.z, v1.w};
      float w0 = wbuf[(ci*3+0)*64 + co];
      float w1 = wbuf[(ci*3+1)*64 + co];
      float w2 = wbuf[(ci*3+2)*64 + co];
      #pragma unroll
      for (int j = 0; j < 4; ++j) {
        acc[j] = fmaf(w0, rr[j],   acc[j]);
        acc[j] = fmaf(w1, rr[j+1], acc[j]);
        acc[j] = fmaf(w2, rr[j+2], acc[j]);
      }
    }
    const bool act = (l < 4);
    #pragma unroll
    for (int j = 0; j < 4; ++j) {
      float v = acc[j];
      pb[co*36 + q*4 + j + 1] = act ? lrelu(v) : v;
    }
    __syncthreads();
    if (l < 4) {
      #pragma unroll
      for (int i = 0; i < 6; ++i) ((float4*)wbuf)[tid + i*512] = pf[i];
      __syncthreads();
    }
    float* tp = pa; pa = pb; pb = tp;
  }
  const float* zf = pa;  // final z, 64ch x 32t (+pads)

  // ---- y0 = nz_init 1x1 conv -> bf16 into tileA rows t+1 ----
  {
    float acc[4];
    float bv = nzi_b[co];
    #pragma unroll
    for (int j = 0; j < 4; ++j) acc[j] = bv;
    #pragma unroll 8
    for (int c = 0; c < 64; ++c) {
      float wv = nzL[c*64 + co];
      const float* rw = zf + c*36 + q*4 + 1;
      #pragma unroll
      for (int j = 0; j < 4; ++j) acc[j] = fmaf(wv, rw[j], acc[j]);
    }
    #pragma unroll
    for (int j = 0; j < 4; ++j)
      tileA[(q*4 + j + 1)*72 + co] = (short)f2bf(acc[j]);
  }
  if (tid < 64) { tileA[tid] = 0; tileA[33*72 + tid] = 0; }

  // ---- amp / freq projections from LDS ----
  #pragma unroll
  for (int tt = 0; tt < 2; ++tt) {
    int task = tid + 512*tt;
    int o = task & 31, t = task >> 5;
    float aa = amp_b[o], ff = frq_b[o];
    #pragma unroll 8
    for (int c = 0; c < 64; ++c) {
      float zv = zf[c*36 + t + 1];
      aa = fmaf(awL[c*32 + o], zv, aa);
      ff = fmaf(fwL[c*32 + o], zv, ff);
    }
    aa = fabsf(aa);
    float sg = 1.f / (1.f + expf(-ff));
    float fq = LOWEST_FREQ_F + sg * (1.f - LOWEST_FREQ_F);
    amp_o[b*1024 + o*32 + t] = aa;
    frq_o[b*1024 + o*32 + t] = fq;
    fl[o*33 + t] = fq;
  }
  __syncthreads();

  // ---- fp64 phase boundary prefix: store frac(P[i]/2) ----
  if (tid < 32) {
    const int o = tid;
    double P = 256.0 * (double)fl[o*33];
    double h = P * 0.5;
    ph_o[b*1024 + o*32] = (float)(h - floor(h));
    for (int i = 1; i < 32; ++i) {
      P += 256.0 * ((double)fl[o*33 + i - 1] + (double)fl[o*33 + i]);
      h = P * 0.5;
      ph_o[b*1024 + o*32 + i] = (float)(h - floor(h));
    }
  }

  // ---- noise layers 0..2 in LDS: T 32 -> 64 -> 128 -> 256 ----
  noise_layer<32> (tileA, tileB, wfold + 0*16384, nzu_b + 0*64, tid);
  noise_layer<64> (tileB, tileA, wfold + 1*16384, nzu_b + 1*64, tid);
  noise_layer<128>(tileA, tileB, wfold + 2*16384, nzu_b + 2*64, tid);

  // write y3 [b][t][co] (T=256), contiguous 16B chunks
  unsigned short* yb = y3 + (size_t)b * 16384;
  for (int c = tid; c < 2048; c += 512) {
    int row = c >> 3, pos = (c & 7) << 3;
    *(bf16x8*)(yb + c*8) = *(const bf16x8*)&tileB[(row + 1)*72 + pos];
  }
}

// ---------------------------------------------------------------------------
// Global-to-global MFMA up-conv layer, [b][t][co] layout.
// ---------------------------------------------------------------------------
template<int STILE>
__global__ __launch_bounds__(256) void mfma_up_t(
    const unsigned short* __restrict__ in, unsigned short* __restrict__ out,
    const short* __restrict__ wf, const float* __restrict__ bias, int Tin)
{
  constexpr int ROWS = STILE + 2;
  constexpr int G    = STILE / 64;   // n-tiles per wave (n-tiles total = 2G)
  __shared__ __align__(16) short lB[ROWS * 72];

  const int b   = blockIdx.y;
  const int s0  = blockIdx.x * STILE;
  const int tid = threadIdx.x;
  const int L   = tid & 63;
  const int w   = tid >> 6;
  const int mt  = w & 1;
  const int ng  = w >> 1;

  bf16x8 Af[4][4];
  {
    const short* wb = wf + (mt*32 + (L & 31))*64 + ((L >> 5) << 3);
    #pragma unroll
    for (int pd = 0; pd < 4; ++pd)
      #pragma unroll
      for (int ks = 0; ks < 4; ++ks)
        Af[pd][ks] = *(const bf16x8*)(wb + pd*4096 + ks*16);
  }

  const unsigned short* inb = in + (size_t)b * Tin * 64;
  for (int c = tid; c < ROWS*8; c += 256) {
    int row = c >> 3, pos = (c & 7) << 3;
    int g = s0 - 1 + row;
    bf16x8 v = {0,0,0,0,0,0,0,0};
    if (g >= 0 && g < Tin) v = *(const bf16x8*)(inb + (size_t)g*64 + pos);
    *(bf16x8*)&lB[row*72 + pos] = v;
  }

  f32x16 binit;
  #pragma unroll
  for (int r = 0; r < 16; ++r)
    binit[r] = bias[mt*32 + (r & 3) + 8*(r >> 2) + 4*(L >> 5)];

  __syncthreads();

  unsigned short* outb = out + (size_t)b * (2*Tin) * 64;
  #pragma unroll
  for (int nt = 0; nt < G; ++nt) {
    int s_loc = ng*(32*G) + nt*32 + (L & 31);
    const short* bp = lB + s_loc*72 + ((L >> 5) << 3);
    f32x16 Ce = binit, Co = binit;
    #pragma unroll
    for (int ks = 0; ks < 4; ++ks) {
      bf16x8 Bm = *(const bf16x8*)(bp + ks*16);
      bf16x8 B0 = *(const bf16x8*)(bp + 72 + ks*16);
      bf16x8 Bp = *(const bf16x8*)(bp + 144 + ks*16);
      Ce = __builtin_amdgcn_mfma_f32_32x32x16_bf16(Af[0][ks], Bm, Ce, 0, 0, 0);
      Ce = __builtin_amdgcn_mfma_f32_32x32x16_bf16(Af[1][ks], B0, Ce, 0, 0, 0);
      Co = __builtin_amdgcn_mfma_f32_32x32x16_bf16(Af[2][ks], B0, Co, 0, 0, 0);
      Co = __builtin_amdgcn_mfma_f32_32x32x16_bf16(Af[3][ks], Bp, Co, 0, 0, 0);
    }
    int t0 = (s0 + s_loc) * 2;
    #pragma unroll
    for (int q4 = 0; q4 < 4; ++q4) {
      int co0 = mt*32 + 8*q4 + 4*(L >> 5);
      uint2 ve, vo;
      ve.x = pack2(lrelu(Ce[4*q4+0]), lrelu(Ce[4*q4+1]));
      ve.y = pack2(lrelu(Ce[4*q4+2]), lrelu(Ce[4*q4+3]));
      vo.x = pack2(lrelu(Co[4*q4+0]), lrelu(Co[4*q4+1]));
      vo.y = pack2(lrelu(Co[4*q4+2]), lrelu(Co[4*q4+3]));
      *(uint2*)(outb + (size_t)t0*64 + co0)     = ve;
      *(uint2*)(outb + (size_t)(t0+1)*64 + co0) = vo;
    }
  }
}

// ---------------------------------------------------------------------------
// Final fused: layer 6 (Tin=2048 -> 4096, y7 stays in LDS) + nz_final coeffs
// + squared + length-4 ortho rfft/irfft filter + oscillator bank (o-outer,
// per-osc state loaded once for the thread's 4 samples). Writes out once.
// ---------------------------------------------------------------------------
__global__ __launch_bounds__(256) void final_fused(
    const unsigned short* __restrict__ in,    // y6 [b][t][co], Tin=2048
    const short* __restrict__ wf, const float* __restrict__ bias,
    const float* __restrict__ nzf_w, const float* __restrict__ nzf_b,
    const float* __restrict__ noise,
    const float* __restrict__ amp, const float* __restrict__ frq,
    const float* __restrict__ ph, float* __restrict__ out)
{
  constexpr int STILE = 128, Tin = 2048, ROWS = STILE + 2, G = STILE / 64;
  __shared__ __align__(16) short lB[ROWS * 72];     // 18720 B
  __shared__ __align__(16) short yT[256 * 72];      // 36864 B
  __shared__ float al[1024], fqv[1024], pl[1024];   // 12288 B
  __shared__ float wl[192];

  const int b   = blockIdx.y;
  const int s0  = blockIdx.x * STILE;
  const int tid = threadIdx.x;
  const int L   = tid & 63;
  const int w   = tid >> 6;
  const int mt  = w & 1;
  const int ng  = w >> 1;

  for (int i = tid; i < 1024; i += 256) {
    al[i]  = amp[b*1024 + i];
    fqv[i] = frq[b*1024 + i];
    pl[i]  = ph[b*1024 + i];
  }
  if (tid < 192) { int o = tid >> 6, c = tid & 63; wl[c*3 + o] = nzf_w[tid]; }

  bf16x8 Af[4][4];
  {
    const short* wb = wf + (mt*32 + (L & 31))*64 + ((L >> 5) << 3);
    #pragma unroll
    for (int pd = 0; pd < 4; ++pd)
      #pragma unroll
      for (int ks = 0; ks < 4; ++ks)
        Af[pd][ks] = *(const bf16x8*)(wb + pd*4096 + ks*16);
  }

  const unsigned short* inb = in + (size_t)b * Tin * 64;
  for (int c = tid; c < ROWS*8; c += 256) {
    int row = c >> 3, pos = (c & 7) << 3;
    int g = s0 - 1 + row;
    bf16x8 v = {0,0,0,0,0,0,0,0};
    if (g >= 0 && g < Tin) v = *(const bf16x8*)(inb + (size_t)g*64 + pos);
    *(bf16x8*)&lB[row*72 + pos] = v;
  }

  f32x16 binit;
  #pragma unroll
  for (int r = 0; r < 16; ++r)
    binit[r] = bias[mt*32 + (r & 3) + 8*(r >> 2) + 4*(L >> 5)];

  __syncthreads();

  #pragma unroll
  for (int nt = 0; nt < G; ++nt) {
    int s_loc = ng*(32*G) + nt*32 + (L & 31);
    const short* bp = lB + s_loc*72 + ((L >> 5) << 3);
    f32x16 Ce = binit, Co = binit;
    #pragma unroll
    for (int ks = 0; ks < 4; ++ks) {
      bf16x8 Bm = *(const bf16x8*)(bp + ks*16);
      bf16x8 B0 = *(const bf16x8*)(bp + 72 + ks*16);
      bf16x8 Bp = *(const bf16x8*)(bp + 144 + ks*16);
      Ce = __builtin_amdgcn_mfma_f32_32x32x16_bf16(Af[0][ks], Bm, Ce, 0, 0, 0);
      Ce = __builtin_amdgcn_mfma_f32_32x32x16_bf16(Af[1][ks], B0, Ce, 0, 0, 0);
      Co = __builtin_amdgcn_mfma_f32_32x32x16_bf16(Af[2][ks], B0, Co, 0, 0, 0);
      Co = __builtin_amdgcn_mfma_f32_32x32x16_bf16(Af[3][ks], Bp, Co, 0, 0, 0);
    }
    #pragma unroll
    for (int q4 = 0; q4 < 4; ++q4) {
      int co0 = mt*32 + 8*q4 + 4*(L >> 5);
      uint2 ve, vo;
      ve.x = pack2(lrelu(Ce[4*q4+0]), lrelu(Ce[4*q4+1]));
      ve.y = pack2(lrelu(Ce[4*q4+2]), lrelu(Ce[4*q4+3]));
      vo.x = pack2(lrelu(Co[4*q4+0]), lrelu(Co[4*q4+1]));
      vo.y = pack2(lrelu(Co[4*q4+2]), lrelu(Co[4*q4+3]));
      *(uint2*)&yT[(2*s_loc)*72 + co0]     = ve;
      *(uint2*)&yT[(2*s_loc + 1)*72 + co0] = vo;
    }
  }
  __syncthreads();

  // epilogue: one thread per frame (local t = tid)
  {
    const short* yr = &yT[tid * 72];
    float c0 = nzf_b[0], c1 = nzf_b[1], c2 = nzf_b[2];
    #pragma unroll
    for (int c8 = 0; c8 < 8; ++c8) {
      bf16x8 v = *(const bf16x8*)(yr + c8*8);
      #pragma unroll
      for (int j = 0; j < 8; ++j) {
        float yv = bf2f((unsigned short)v[j]);
        int c = c8*8 + j;
        c0 = fmaf(wl[c*3+0], yv, c0);
        c1 = fmaf(wl[c*3+1], yv, c1);
        c2 = fmaf(wl[c*3+2], yv, c2);
      }
    }
    c0 *= c0; c1 *= c1; c2 *= c2;

    const int fb = 2*s0 + tid;                 // frame in [0,4096)
    const float4 n = *(const float4*)(noise + ((size_t)b*4096 + fb)*4);
    float F0  = c0 * (n.x + n.y + n.z + n.w) * 0.5f;
    float F1r = c1 * (n.x - n.z) * 0.5f;
    float F1i = -(c1 * (n.y - n.w) * 0.5f);
    float F2  = c2 * (n.x - n.y + n.z - n.w) * 0.5f;
    float r0 = 0.5f * (F0 + 2.f*F1r + F2);
    float r1 = 0.5f * (F0 - 2.f*F1i - F2);
    float r2 = 0.5f * (F0 - 2.f*F1r + F2);
    float r3 = 0.5f * (F0 + 2.f*F1i - F2);

    const int t0 = fb * 4;
    float s0a = 0.f, s1a = 0.f, s2a = 0.f, s3a = 0.f;
    if (t0 < 256) {                      // head: freq=f0, amp=a0
      const float tp = (float)(t0 + 1) * 0.5f;
      #pragma unroll 4
      for (int o = 0; o < 32; ++o) {
        float f0 = fqv[o*32], am = al[o*32];
        float hf = 0.5f * f0;
        float v0 = tp * f0, v1 = v0 + hf, v2 = v1 + hf, v3 = v2 + hf;
        s0a += am * sin_rev(v0 - floorf(v0));
        s1a += am * sin_rev(v1 - floorf(v1));
        s2a += am * sin_rev(v2 - floorf(v2));
        s3a += am * sin_rev(v3 - floorf(v3));
      }
    } else if (t0 >= 16128) {            // tail: freq=f31, amp=a31
      const float tp = (float)(t0 - 16127) * 0.5f;
      #pragma unroll 4
      for (int o = 0; o < 32; ++o) {
        float f0 = fqv[o*32 + 31], am = al[o*32 + 31], p = pl[o*32 + 31];
        float hf = 0.5f * f0;
        float v0 = p + tp * f0, v1 = v0 + hf, v2 = v1 + hf, v3 = v2 + hf;
        s0a += am * sin_rev(v0 - floorf(v0));
        s1a += am * sin_rev(v1 - floorf(v1));
        s2a += am * sin_rev(v2 - floorf(v2));
        s3a += am * sin_rev(v3 - floorf(v3));
      }
    } else {                             // middle: same interp cell for all 4
      const int i  = (t0 - 256) >> 9;
      const int m0 = (t0 - 256) & 511;
      float mm[4], fa[4], mq[4];
      #pragma unroll
      for (int js = 0; js < 4; ++js) {
        float mmv = (float)(m0 + 1 + js);
        mm[js] = mmv;
        fa[js] = ((float)(m0 + js) + 0.5f) * (1.f/512.f);
        mq[js] = mmv * mmv * (1.f/1024.f);
      }
      #pragma unroll 4
      for (int o = 0; o < 32; ++o) {
        float f0 = fqv[o*32 + i], f1 = fqv[o*32 + i + 1];
        float a0 = al[o*32 + i],  a1 = al[o*32 + i + 1];
        float p  = pl[o*32 + i];
        float df = f1 - f0, da = a1 - a0;
        #pragma unroll
        for (int js = 0; js < 4; ++js) {
          float av   = fmaf(da, fa[js], a0);
          float part = fmaf(df, mq[js], mm[js] * f0);
          float v    = fmaf(part, 0.5f, p);
          float fr   = v - floorf(v);
          float sv   = av * sin_rev(fr);
          if      (js == 0) s0a += sv;
          else if (js == 1) s1a += sv;
          else if (js == 2) s2a += sv;
          else              s3a += sv;
        }
      }
    }
    float4 res = make_float4(s0a + r0, s1a + r1, s2a + r2, s3a + r3);
    *(float4*)(out + ((size_t)b*4096 + fb)*4) = res;
  }
}

// ---------------------------------------------------------------------------
extern "C" void kernel_launch(void* const* d_in, const int* in_sizes, int n_in,
                              void* d_out, int out_size, void* d_ws, size_t ws_size,
                              hipStream_t stream) {
  (void)in_sizes; (void)n_in; (void)out_size; (void)ws_size;
  const float* x     = (const float*)d_in[0];
  const float* noise = (const float*)d_in[1];
  const float* net_w = (const float*)d_in[2];
  const float* net_b = (const float*)d_in[3];
  const float* fin_w = (const float*)d_in[4];
  const float* fin_b = (const float*)d_in[5];
  const float* amp_w = (const float*)d_in[6];
  const float* amp_b = (const float*)d_in[7];
  const float* frq_w = (const float*)d_in[8];
  const float* frq_b = (const float*)d_in[9];
  const float* nzi_w = (const float*)d_in[10];
  const float* nzi_b = (const float*)d_in[11];
  const float* nzu_w = (const float*)d_in[12];
  const float* nzu_b = (const float*)d_in[13];
  const float* nzf_w = (const float*)d_in[14];
  const float* nzf_b = (const float*)d_in[15];
  float* out = (float*)d_out;

  // workspace (~31 MiB)
  short* y3    = (short*)d_ws;                       // 64*256*64
  short* y4    = y3 + (size_t)64*256*64;             // 64*512*64
  short* y5    = y4 + (size_t)64*512*64;             // 64*1024*64
  short* y6    = y5 + (size_t)64*1024*64;            // 64*2048*64
  short* wfold = y6 + (size_t)64*2048*64;            // 7*16384
  float* wtF   = (float*)(wfold + 7*16384);          // 5*12288
  float* awT   = wtF + 61440;                        // 2048
  float* fwT   = awT + 2048;                         // 2048
  float* nzT   = fwT + 2048;                         // 4096
  float* ampv  = nzT + 4096;                         // 65536
  float* frqv  = ampv + 65536;
  float* phv   = frqv + 65536;

  prep_kernel<<<dim3(720), dim3(256), 0, stream>>>(
      net_w, fin_w, amp_w, frq_w, nzi_w, nzu_w, wtF, awT, fwT, nzT, wfold);

  z_front<<<dim3(64), dim3(512), 0, stream>>>(
      x, wtF, net_b, fin_b, awT, amp_b, fwT, frq_b, nzT, nzi_b,
      wfold, nzu_b, (unsigned short*)y3, ampv, frqv, phv);

  mfma_up_t<64> <<<dim3(4, 64), dim3(256), 0, stream>>>(
      (unsigned short*)y3, (unsigned short*)y4, wfold + 3*16384, nzu_b + 3*64, 256);
  mfma_up_t<128><<<dim3(4, 64), dim3(256), 0, stream>>>(
      (unsigned short*)y4, (unsigned short*)y5, wfold + 4*16384, nzu_b + 4*64, 512);
  mfma_up_t<128><<<dim3(8, 64), dim3(256), 0, stream>>>(
      (unsigned short*)y5, (unsigned short*)y6, wfold + 5*16384, nzu_b + 5*64, 1024);

  final_fused<<<dim3(16, 64), dim3(256), 0, stream>>>(
      (unsigned short*)y6, wfold + 6*16384, nzu_b + 6*64,
      nzf_w, nzf_b, noise, ampv, frqv, phv, out);
}